// Round 3
// baseline (1847.314 us; speedup 1.0000x reference)
//
#include <hip/hip_runtime.h>
#include <hip/hip_fp16.h>
#include <cstdint>

#define IN_DIM   128
#define HIDC     64
#define HEADS    4
#define OUT_DIM  40
#define NEG_SLOPE 0.2f
#define BN_EPS   1e-5f

typedef unsigned short ushortt;

__device__ __forceinline__ float bfval(ushortt u) {
    return __uint_as_float(((unsigned)u) << 16);
}
__device__ __forceinline__ ushortt f2bf(float f) {
    unsigned u = __float_as_uint(f);
    u += 0x7fffu + ((u >> 16) & 1u);
    return (ushortt)(u >> 16);
}

// ---------------- CSR build ----------------
__global__ void detect_kernel(const unsigned int* __restrict__ e, int* __restrict__ flag) {
    __shared__ int any;
    if (threadIdx.x == 0) any = 0;
    __syncthreads();
    for (int i = threadIdx.x; i < 1024; i += 256)
        if (e[2 * i + 1] != 0u) any = 1;
    __syncthreads();
    if (threadIdx.x == 0) flag[0] = any ? 0 : 1;   // 1 => int64
}

__device__ __forceinline__ int load_idx(const int* ei, int is64, long long pos) {
    return is64 ? ei[2 * pos] : ei[pos];
}

__global__ void hist_kernel(const int* __restrict__ ei, const int* __restrict__ flag,
                            int* __restrict__ deg, int E, int Etot) {
    int i = blockIdx.x * 256 + threadIdx.x;
    if (i >= Etot) return;
    int is64 = flag[0];
    int dst = (i < E) ? load_idx(ei, is64, (long long)E + i) : (i - E);
    atomicAdd(&deg[dst], 1);
}

__global__ void scan_kernel(int* __restrict__ data, int n) {
    __shared__ int wsum[16];
    __shared__ int chunk_total;
    int lane = threadIdx.x & 63;
    int w = threadIdx.x >> 6;
    int carry = 0;
    for (int base = 0; base < n; base += 1024) {
        int i = base + (int)threadIdx.x;
        int v = (i < n) ? data[i] : 0;
        int x = v;
        #pragma unroll
        for (int ofs = 1; ofs < 64; ofs <<= 1) {
            int y = __shfl_up(x, ofs);
            if (lane >= ofs) x += y;
        }
        if (lane == 63) wsum[w] = x;
        __syncthreads();
        if (w == 0) {
            int s = (lane < 16) ? wsum[lane] : 0;
            #pragma unroll
            for (int ofs = 1; ofs < 16; ofs <<= 1) {
                int y = __shfl_up(s, ofs);
                if (lane >= ofs) s += y;
            }
            if (lane < 16) wsum[lane] = s;
            if (lane == 15) chunk_total = s;
        }
        __syncthreads();
        int woff = (w > 0) ? wsum[w - 1] : 0;
        if (i < n) data[i] = (x + woff) - v + carry;
        int ct = chunk_total;
        __syncthreads();
        carry += ct;
    }
}

__global__ void scatter_kernel(const int* __restrict__ ei, const int* __restrict__ flag,
                               int* __restrict__ cursor, int* __restrict__ csr,
                               int E, int Etot) {
    int i = blockIdx.x * 256 + threadIdx.x;
    if (i >= Etot) return;
    int is64 = flag[0];
    int src, dst;
    if (i < E) {
        src = load_idx(ei, is64, i);
        dst = load_idx(ei, is64, (long long)E + i);
    } else {
        src = dst = i - E;
    }
    int pos = atomicAdd(&cursor[dst], 1);
    csr[pos] = src;
}

// ---------------- fold bias+BN into scale/shift ----------------
__global__ void prep_bn_kernel(const float* b1, const float* g1, const float* bb1,
                               const float* m1, const float* v1,
                               const float* b2, const float* g2, const float* bb2,
                               const float* m2, const float* v2,
                               float* __restrict__ bnsc, float* __restrict__ bnsh) {
    int t = threadIdx.x;
    if (t < 256) {
        float s = g1[t] * rsqrtf(v1[t] + BN_EPS);
        bnsc[t] = s;
        bnsh[t] = (b1[t] - m1[t]) * s + bb1[t];
    } else if (t < 320) {
        int c = t - 256;
        float s = g2[c] * rsqrtf(v2[c] + BN_EPS);
        bnsc[t] = s;
        bnsh[t] = (b2[c] - m2[c]) * s + bb2[c];
    }
}

// ---------------- GEMM layer1: x[N][128] @ W1[128][256] -> hBc1 (chunked bf16), a_s4/a_d4 ----------------
__launch_bounds__(256)
__global__ void gemm1_kernel(const float* __restrict__ A, const float* __restrict__ W,
                             const float* __restrict__ atts, const float* __restrict__ attd,
                             ushortt* __restrict__ hBc, float* __restrict__ a_s4,
                             float* __restrict__ a_d4, int N) {
    __shared__ float As[32 * 128];
    int m0 = blockIdx.x * 32;
    int t = threadIdx.x;
    for (int idx = t; idx < 32 * 128; idx += 256) {
        int r = idx >> 7, c = idx & 127;
        int mm = m0 + r;
        As[idx] = (mm < N) ? A[(size_t)mm * 128 + c] : 0.f;
    }
    __syncthreads();
    int tx = t & 63, ty = t >> 6;
    float acc[8][4] = {};
    const float* Ap = &As[(ty * 8) << 7];
    #pragma unroll 2
    for (int k = 0; k < 128; ++k) {
        float b0 = W[k * 256 + tx];
        float b1 = W[k * 256 + tx + 64];
        float b2 = W[k * 256 + tx + 128];
        float b3 = W[k * 256 + tx + 192];
        #pragma unroll
        for (int i = 0; i < 8; ++i) {
            float a = Ap[(i << 7) + k];
            acc[i][0] += a * b0; acc[i][1] += a * b1;
            acc[i][2] += a * b2; acc[i][3] += a * b3;
        }
    }
    #pragma unroll
    for (int i = 0; i < 8; ++i) {
        int mm = m0 + ty * 8 + i;
        if (mm < N) {
            #pragma unroll
            for (int c = 0; c < 4; ++c) {
                float v = acc[i][c];
                int g = c * 64 + tx;
                hBc[((size_t)(g >> 5) * N + mm) * 32 + (g & 31)] = f2bf(v);
                float ps = v * atts[g];
                float pd = v * attd[g];
                #pragma unroll
                for (int o = 32; o; o >>= 1) { ps += __shfl_xor(ps, o); pd += __shfl_xor(pd, o); }
                if (tx == 0) { a_s4[(size_t)mm * 4 + c] = ps; a_d4[(size_t)mm * 4 + c] = pd; }
            }
        }
    }
}

// ---------------- GEMM layers 2/3 -> chunked bf16 hB + a_s/a_d ----------------
template <int K, int NC>
__launch_bounds__(256)
__global__ void gemm_attn_kernel(const float* __restrict__ A, const float* __restrict__ W,
                                 const float* __restrict__ atts, const float* __restrict__ attd,
                                 ushortt* __restrict__ hBc, float* __restrict__ a_s,
                                 float* __restrict__ a_d, int N) {
    __shared__ float As[32 * K];
    int m0 = blockIdx.x * 32;
    int t = threadIdx.x;
    for (int idx = t; idx < 32 * K; idx += 256) {
        int r = idx / K, c = idx % K;
        int mm = m0 + r;
        As[idx] = (mm < N) ? A[(size_t)mm * K + c] : 0.f;
    }
    __syncthreads();
    int tx = t & 63, ty = t >> 6;
    float acc[8] = {};
    const float* Ap = &As[(ty * 8) * K];
    #pragma unroll 2
    for (int k = 0; k < K; ++k) {
        float bv = (tx < NC) ? W[k * NC + tx] : 0.f;
        #pragma unroll
        for (int i = 0; i < 8; ++i) acc[i] += Ap[i * K + k] * bv;
    }
    #pragma unroll
    for (int i = 0; i < 8; ++i) {
        int mm = m0 + ty * 8 + i;
        if (mm < N) {
            if (tx < NC) {
                if (NC == 64)
                    hBc[((size_t)(tx >> 4) * N + mm) * 16 + (tx & 15)] = f2bf(acc[i]);
                else // NC == 40: 8 chunks of 5 channels
                    hBc[((size_t)(tx / 5) * N + mm) * 5 + (tx % 5)] = f2bf(acc[i]);
            }
            float ps = (tx < NC) ? acc[i] * atts[tx] : 0.f;
            float pd = (tx < NC) ? acc[i] * attd[tx] : 0.f;
            #pragma unroll
            for (int o = 32; o; o >>= 1) { ps += __shfl_xor(ps, o); pd += __shfl_xor(pd, o); }
            if (tx == 0) { a_s[mm] = ps; a_d[mm] = pd; }
        }
    }
}

// ---------------- alpha materialization, layer 1 (4 heads): block=node, wave=head ----------------
__launch_bounds__(256)
__global__ void alpha4_kernel(const int* __restrict__ off, const int* __restrict__ csr,
                              const float* __restrict__ a_s4, const float* __restrict__ a_d4,
                              __half* __restrict__ al, int N, int Etot) {
    int node = blockIdx.x;
    if (node >= N) return;
    int head = threadIdx.x >> 6, lane = threadIdx.x & 63;
    int beg = off[node], end = off[node + 1];
    float ad = a_d4[(size_t)node * 4 + head];
    float m = -INFINITY;
    for (int j = beg + lane; j < end; j += 64) {
        float v = a_s4[(size_t)csr[j] * 4 + head] + ad;
        v = v > 0.f ? v : NEG_SLOPE * v;
        m = fmaxf(m, v);
    }
    #pragma unroll
    for (int o = 32; o; o >>= 1) m = fmaxf(m, __shfl_xor(m, o));
    float ss = 0.f;
    for (int j = beg + lane; j < end; j += 64) {
        float v = a_s4[(size_t)csr[j] * 4 + head] + ad;
        v = v > 0.f ? v : NEG_SLOPE * v;
        ss += __expf(v - m);
    }
    #pragma unroll
    for (int o = 32; o; o >>= 1) ss += __shfl_xor(ss, o);
    float inv = 1.f / (ss + 1e-16f);
    __half* alh = al + (size_t)head * Etot;
    for (int j = beg + lane; j < end; j += 64) {
        float v = a_s4[(size_t)csr[j] * 4 + head] + ad;
        v = v > 0.f ? v : NEG_SLOPE * v;
        alh[j] = __float2half(__expf(v - m) * inv);
    }
}

// ---------------- alpha materialization, single head: wave=node ----------------
__launch_bounds__(256)
__global__ void alpha1w_kernel(const int* __restrict__ off, const int* __restrict__ csr,
                               const float* __restrict__ a_s, const float* __restrict__ a_d,
                               __half* __restrict__ al, int N) {
    int node = blockIdx.x * 4 + (threadIdx.x >> 6);
    int lane = threadIdx.x & 63;
    if (node >= N) return;
    int beg = off[node], end = off[node + 1];
    float ad = a_d[node];
    float m = -INFINITY;
    for (int j = beg + lane; j < end; j += 64) {
        float v = a_s[csr[j]] + ad;
        v = v > 0.f ? v : NEG_SLOPE * v;
        m = fmaxf(m, v);
    }
    #pragma unroll
    for (int o = 32; o; o >>= 1) m = fmaxf(m, __shfl_xor(m, o));
    float ss = 0.f;
    for (int j = beg + lane; j < end; j += 64) {
        float v = a_s[csr[j]] + ad;
        v = v > 0.f ? v : NEG_SLOPE * v;
        ss += __expf(v - m);
    }
    #pragma unroll
    for (int o = 32; o; o >>= 1) ss += __shfl_xor(ss, o);
    float inv = 1.f / (ss + 1e-16f);
    for (int j = beg + lane; j < end; j += 64) {
        float v = a_s[csr[j]] + ad;
        v = v > 0.f ? v : NEG_SLOPE * v;
        al[j] = __float2half(__expf(v - m) * inv);
    }
}

// ---------------- PV layer 1: 8 chunks x 32 ch, chunk pinned to XCD via blockIdx%8 ----------------
__launch_bounds__(256)
__global__ void pv1_kernel(const int* __restrict__ off, const int* __restrict__ csr,
                           const __half* __restrict__ al, const ushortt* __restrict__ hBc,
                           const float* __restrict__ bnsc, const float* __restrict__ bnsh,
                           float* __restrict__ act, int N, int Etot) {
    int chunk = blockIdx.x & 7;
    int node = (blockIdx.x >> 3) * 4 + (threadIdx.x >> 6);
    int lane = threadIdx.x & 63;
    if (node >= N) return;
    int k = lane >> 4, cp = lane & 15;
    int beg = off[node], end = off[node + 1];
    const ushortt* hb = hBc + (size_t)chunk * N * 32;
    const __half* alh = al + (size_t)(chunk >> 1) * Etot;
    float a0 = 0.f, a1 = 0.f;
    for (int j0 = beg; j0 < end; j0 += 4) {
        int j = j0 + k;
        int jj = (j < end) ? j : beg;
        float av = (j < end) ? __half2float(alh[jj]) : 0.f;
        int s = csr[jj];
        unsigned hv = *(const unsigned*)(hb + (size_t)s * 32 + cp * 2);
        a0 += av * bfval((ushortt)(hv & 0xffffu));
        a1 += av * bfval((ushortt)(hv >> 16));
    }
    a0 += __shfl_xor(a0, 16); a0 += __shfl_xor(a0, 32);
    a1 += __shfl_xor(a1, 16); a1 += __shfl_xor(a1, 32);
    if (lane < 16) {
        int g = chunk * 32 + 2 * lane;
        float v0 = a0 * bnsc[g] + bnsh[g];
        float v1 = a1 * bnsc[g + 1] + bnsh[g + 1];
        v0 = v0 > 0.f ? v0 : expm1f(v0);
        v1 = v1 > 0.f ? v1 : expm1f(v1);
        *(float2*)&act[(size_t)node * 256 + g] = make_float2(v0, v1);
    }
}

// ---------------- PV layer 2: 4 chunks x 16 ch ----------------
__launch_bounds__(256)
__global__ void pv2_kernel(const int* __restrict__ off, const int* __restrict__ csr,
                           const __half* __restrict__ al, const ushortt* __restrict__ hBc,
                           const float* __restrict__ bnsc, const float* __restrict__ bnsh,
                           float* __restrict__ act2, int N) {
    int chunk = blockIdx.x & 3;
    int node = (blockIdx.x >> 2) * 4 + (threadIdx.x >> 6);
    int lane = threadIdx.x & 63;
    if (node >= N) return;
    int k = lane >> 3, cp = lane & 7;
    int beg = off[node], end = off[node + 1];
    const ushortt* hb = hBc + (size_t)chunk * N * 16;
    float a0 = 0.f, a1 = 0.f;
    for (int j0 = beg; j0 < end; j0 += 8) {
        int j = j0 + k;
        int jj = (j < end) ? j : beg;
        float av = (j < end) ? __half2float(al[jj]) : 0.f;
        int s = csr[jj];
        unsigned hv = *(const unsigned*)(hb + (size_t)s * 16 + cp * 2);
        a0 += av * bfval((ushortt)(hv & 0xffffu));
        a1 += av * bfval((ushortt)(hv >> 16));
    }
    a0 += __shfl_xor(a0, 8); a0 += __shfl_xor(a0, 16); a0 += __shfl_xor(a0, 32);
    a1 += __shfl_xor(a1, 8); a1 += __shfl_xor(a1, 16); a1 += __shfl_xor(a1, 32);
    if (lane < 8) {
        int g = chunk * 16 + 2 * lane;
        float v0 = a0 * bnsc[256 + g] + bnsh[256 + g];
        float v1 = a1 * bnsc[256 + g + 1] + bnsh[256 + g + 1];
        v0 = v0 > 0.f ? v0 : expm1f(v0);
        v1 = v1 > 0.f ? v1 : expm1f(v1);
        *(float2*)&act2[(size_t)node * 64 + g] = make_float2(v0, v1);
    }
}

// ---------------- PV layer 3: 8 chunks x 5 ch -> tmp3 fp32 [N][40] ----------------
__launch_bounds__(256)
__global__ void pv3_kernel(const int* __restrict__ off, const int* __restrict__ csr,
                           const __half* __restrict__ al, const ushortt* __restrict__ hBc,
                           float* __restrict__ tmp3, int N) {
    int chunk = blockIdx.x & 7;
    int node = (blockIdx.x >> 3) * 4 + (threadIdx.x >> 6);
    int lane = threadIdx.x & 63;
    if (node >= N) return;
    int k = lane >> 3, cc = lane & 7;
    int beg = off[node], end = off[node + 1];
    const ushortt* hb = hBc + (size_t)chunk * N * 5;
    float a = 0.f;
    for (int j0 = beg; j0 < end; j0 += 8) {
        int j = j0 + k;
        int jj = (j < end) ? j : beg;
        float av = (j < end) ? __half2float(al[jj]) : 0.f;
        int s = csr[jj];
        float hv = (cc < 5) ? bfval(hb[(size_t)s * 5 + cc]) : 0.f;
        a += av * hv;
    }
    a += __shfl_xor(a, 8); a += __shfl_xor(a, 16); a += __shfl_xor(a, 32);
    if (lane < 5) tmp3[(size_t)node * 40 + chunk * 5 + lane] = a;
}

// ---------------- final: bias + log_softmax ----------------
__launch_bounds__(256)
__global__ void final3_kernel(const float* __restrict__ tmp3, const float* __restrict__ b3,
                              float* __restrict__ out, int N) {
    int node = blockIdx.x * 4 + (threadIdx.x >> 6);
    int lane = threadIdx.x & 63;
    if (node >= N) return;
    bool active = lane < OUT_DIM;
    float v = active ? tmp3[(size_t)node * 40 + lane] + b3[lane] : -INFINITY;
    float mx = v;
    #pragma unroll
    for (int o = 32; o; o >>= 1) mx = fmaxf(mx, __shfl_xor(mx, o));
    float ex = active ? __expf(v - mx) : 0.f;
    float s2 = ex;
    #pragma unroll
    for (int o = 32; o; o >>= 1) s2 += __shfl_xor(s2, o);
    if (active) out[(size_t)node * 40 + lane] = v - mx - logf(s2);
}

// ---------------- host ----------------
extern "C" void kernel_launch(void* const* d_in, const int* in_sizes, int n_in,
                              void* d_out, int out_size, void* d_ws, size_t ws_size,
                              hipStream_t stream) {
    const float* x      = (const float*)d_in[0];
    const int*   ei     = (const int*)d_in[1];
    const float* W1     = (const float*)d_in[2];
    const float* att_s1 = (const float*)d_in[3];
    const float* att_d1 = (const float*)d_in[4];
    const float* b1     = (const float*)d_in[5];
    const float* bn1g   = (const float*)d_in[6];
    const float* bn1b   = (const float*)d_in[7];
    const float* bn1m   = (const float*)d_in[8];
    const float* bn1v   = (const float*)d_in[9];
    const float* W2     = (const float*)d_in[10];
    const float* att_s2 = (const float*)d_in[11];
    const float* att_d2 = (const float*)d_in[12];
    const float* b2     = (const float*)d_in[13];
    const float* bn2g   = (const float*)d_in[14];
    const float* bn2b   = (const float*)d_in[15];
    const float* bn2m   = (const float*)d_in[16];
    const float* bn2v   = (const float*)d_in[17];
    const float* W3     = (const float*)d_in[18];
    const float* att_s3 = (const float*)d_in[19];
    const float* att_d3 = (const float*)d_in[20];
    const float* b3     = (const float*)d_in[21];

    const int N    = in_sizes[0] / IN_DIM;
    const int E    = in_sizes[1] / 2;
    const int Etot = E + N;

    int*   wsi = (int*)d_ws;
    float* wsf = (float*)d_ws;
    size_t p = 0;
    int*   off    = wsi + p; p += (size_t)N + 16;
    int*   cursor = wsi + p; p += (size_t)N;
    int*   flag   = wsi + p; p += 16;
    int*   csr    = wsi + p; p += (size_t)Etot;
    float* a_s    = wsf + p; p += (size_t)N * 4;
    float* a_d    = wsf + p; p += (size_t)N * 4;
    float* bnsc   = wsf + p; p += 384;
    float* bnsh   = wsf + p; p += 384;
    size_t H1 = p;           p += (size_t)N * 128;   // hBc1 (N*256 bf16); later hBc3+al3+tmp3
    float* act    = wsf + p; p += (size_t)N * 256;
    size_t AL = p;           p += (size_t)N * 32 + (size_t)Etot / 2 + 32;  // al1 / (hBc2+al2)
    if (ws_size < p * 4) return;

    ushortt* hBc1 = (ushortt*)(wsf + H1);
    __half*  al1  = (__half*)(wsf + AL);
    ushortt* hBc2 = (ushortt*)(wsf + AL);
    __half*  al2  = (__half*)(wsf + AL + (size_t)N * 32);
    ushortt* hBc3 = (ushortt*)(wsf + H1);
    __half*  al3  = (__half*)(wsf + H1 + (size_t)N * 20);
    float*   tmp3 = wsf + H1 + (size_t)N * 20 + (size_t)Etot / 2 + 16;

    float* outp = (float*)d_out;

    // ---- CSR build ----
    hipMemsetAsync(off, 0, ((size_t)N + 1) * sizeof(int), stream);
    detect_kernel<<<1, 256, 0, stream>>>((const unsigned int*)ei, flag);
    {
        int blocks = (Etot + 255) / 256;
        hist_kernel<<<blocks, 256, 0, stream>>>(ei, flag, off, E, Etot);
        scan_kernel<<<1, 1024, 0, stream>>>(off, N + 1);
        hipMemcpyAsync(cursor, off, (size_t)N * sizeof(int), hipMemcpyDeviceToDevice, stream);
        scatter_kernel<<<blocks, 256, 0, stream>>>(ei, flag, cursor, csr, E, Etot);
    }
    prep_bn_kernel<<<1, 384, 0, stream>>>(b1, bn1g, bn1b, bn1m, bn1v,
                                          b2, bn2g, bn2b, bn2m, bn2v, bnsc, bnsh);

    const int gemm_blocks = (N + 31) / 32;
    const int nb4 = (N + 3) / 4;

    // ---- layer 1 ----
    gemm1_kernel<<<gemm_blocks, 256, 0, stream>>>(x, W1, att_s1, att_d1, hBc1, a_s, a_d, N);
    alpha4_kernel<<<N, 256, 0, stream>>>(off, csr, a_s, a_d, al1, N, Etot);
    pv1_kernel<<<nb4 * 8, 256, 0, stream>>>(off, csr, al1, hBc1, bnsc, bnsh, act, N, Etot);

    // ---- layer 2 ----
    gemm_attn_kernel<256, 64><<<gemm_blocks, 256, 0, stream>>>(act, W2, att_s2, att_d2,
                                                               hBc2, a_s, a_d, N);
    alpha1w_kernel<<<nb4, 256, 0, stream>>>(off, csr, a_s, a_d, al2, N);
    pv2_kernel<<<nb4 * 4, 256, 0, stream>>>(off, csr, al2, hBc2, bnsc, bnsh, act, N);

    // ---- layer 3 ----
    gemm_attn_kernel<64, 40><<<gemm_blocks, 256, 0, stream>>>(act, W3, att_s3, att_d3,
                                                              hBc3, a_s, a_d, N);
    alpha1w_kernel<<<nb4, 256, 0, stream>>>(off, csr, a_s, a_d, al3, N);
    pv3_kernel<<<nb4 * 8, 256, 0, stream>>>(off, csr, al3, hBc3, tmp3, N);
    final3_kernel<<<nb4, 256, 0, stream>>>(tmp3, b3, outp, N);
}

// Round 4
// 1101.224 us; speedup vs baseline: 1.6775x; 1.6775x over previous
//
#include <hip/hip_runtime.h>
#include <hip/hip_fp16.h>
#include <cstdint>

#define IN_DIM   128
#define HIDC     64
#define HEADS    4
#define OUT_DIM  40
#define NEG_SLOPE 0.2f
#define BN_EPS   1e-5f

typedef unsigned short ushortt;

__device__ __forceinline__ float bfval(ushortt u) {
    return __uint_as_float(((unsigned)u) << 16);
}
__device__ __forceinline__ ushortt f2bf(float f) {
    unsigned u = __float_as_uint(f);
    u += 0x7fffu + ((u >> 16) & 1u);
    return (ushortt)(u >> 16);
}

// acc[0..7] += a * bf16x8(h)
__device__ __forceinline__ void acc8(float* acc, float a, uint4 h) {
    unsigned u;
    u = h.x;
    acc[0] = fmaf(a, __uint_as_float(u << 16), acc[0]);
    acc[1] = fmaf(a, __uint_as_float(u & 0xffff0000u), acc[1]);
    u = h.y;
    acc[2] = fmaf(a, __uint_as_float(u << 16), acc[2]);
    acc[3] = fmaf(a, __uint_as_float(u & 0xffff0000u), acc[3]);
    u = h.z;
    acc[4] = fmaf(a, __uint_as_float(u << 16), acc[4]);
    acc[5] = fmaf(a, __uint_as_float(u & 0xffff0000u), acc[5]);
    u = h.w;
    acc[6] = fmaf(a, __uint_as_float(u << 16), acc[6]);
    acc[7] = fmaf(a, __uint_as_float(u & 0xffff0000u), acc[7]);
}

// ---------------- CSR build ----------------
__global__ void detect_kernel(const unsigned int* __restrict__ e, int* __restrict__ flag) {
    __shared__ int any;
    if (threadIdx.x == 0) any = 0;
    __syncthreads();
    for (int i = threadIdx.x; i < 1024; i += 256)
        if (e[2 * i + 1] != 0u) any = 1;
    __syncthreads();
    if (threadIdx.x == 0) flag[0] = any ? 0 : 1;   // 1 => int64
}

__device__ __forceinline__ int load_idx(const int* ei, int is64, long long pos) {
    return is64 ? ei[2 * pos] : ei[pos];
}

__global__ void hist_kernel(const int* __restrict__ ei, const int* __restrict__ flag,
                            int* __restrict__ deg, int E, int Etot) {
    int i = blockIdx.x * 256 + threadIdx.x;
    if (i >= Etot) return;
    int is64 = flag[0];
    int dst = (i < E) ? load_idx(ei, is64, (long long)E + i) : (i - E);
    atomicAdd(&deg[dst], 1);
}

__global__ void scan_kernel(int* __restrict__ data, int n) {
    __shared__ int wsum[16];
    __shared__ int chunk_total;
    int lane = threadIdx.x & 63;
    int w = threadIdx.x >> 6;
    int carry = 0;
    for (int base = 0; base < n; base += 1024) {
        int i = base + (int)threadIdx.x;
        int v = (i < n) ? data[i] : 0;
        int x = v;
        #pragma unroll
        for (int ofs = 1; ofs < 64; ofs <<= 1) {
            int y = __shfl_up(x, ofs);
            if (lane >= ofs) x += y;
        }
        if (lane == 63) wsum[w] = x;
        __syncthreads();
        if (w == 0) {
            int s = (lane < 16) ? wsum[lane] : 0;
            #pragma unroll
            for (int ofs = 1; ofs < 16; ofs <<= 1) {
                int y = __shfl_up(s, ofs);
                if (lane >= ofs) s += y;
            }
            if (lane < 16) wsum[lane] = s;
            if (lane == 15) chunk_total = s;
        }
        __syncthreads();
        int woff = (w > 0) ? wsum[w - 1] : 0;
        if (i < n) data[i] = (x + woff) - v + carry;
        int ct = chunk_total;
        __syncthreads();
        carry += ct;
    }
}

__global__ void scatter_kernel(const int* __restrict__ ei, const int* __restrict__ flag,
                               int* __restrict__ cursor, int* __restrict__ csr,
                               int E, int Etot) {
    int i = blockIdx.x * 256 + threadIdx.x;
    if (i >= Etot) return;
    int is64 = flag[0];
    int src, dst;
    if (i < E) {
        src = load_idx(ei, is64, i);
        dst = load_idx(ei, is64, (long long)E + i);
    } else {
        src = dst = i - E;
    }
    int pos = atomicAdd(&cursor[dst], 1);
    csr[pos] = src;
}

// ---------------- fold bias+BN into scale/shift ----------------
__global__ void prep_bn_kernel(const float* b1, const float* g1, const float* bb1,
                               const float* m1, const float* v1,
                               const float* b2, const float* g2, const float* bb2,
                               const float* m2, const float* v2,
                               float* __restrict__ bnsc, float* __restrict__ bnsh) {
    int t = threadIdx.x;
    if (t < 256) {
        float s = g1[t] * rsqrtf(v1[t] + BN_EPS);
        bnsc[t] = s;
        bnsh[t] = (b1[t] - m1[t]) * s + bb1[t];
    } else if (t < 320) {
        int c = t - 256;
        float s = g2[c] * rsqrtf(v2[c] + BN_EPS);
        bnsc[t] = s;
        bnsh[t] = (b2[c] - m2[c]) * s + bb2[c];
    }
}

// ---------------- GEMM layer1: x[N][128] @ W1[128][256] -> hB bf16 [N][256], a_s4/a_d4 ----------------
__launch_bounds__(256)
__global__ void gemm1_kernel(const float* __restrict__ A, const float* __restrict__ W,
                             const float* __restrict__ atts, const float* __restrict__ attd,
                             ushortt* __restrict__ hB, float* __restrict__ a_s4,
                             float* __restrict__ a_d4, int N) {
    __shared__ float As[32 * 128];
    int m0 = blockIdx.x * 32;
    int t = threadIdx.x;
    for (int idx = t; idx < 32 * 128; idx += 256) {
        int r = idx >> 7, c = idx & 127;
        int mm = m0 + r;
        As[idx] = (mm < N) ? A[(size_t)mm * 128 + c] : 0.f;
    }
    __syncthreads();
    int tx = t & 63, ty = t >> 6;
    float acc[8][4] = {};
    const float* Ap = &As[(ty * 8) << 7];
    #pragma unroll 2
    for (int k = 0; k < 128; ++k) {
        float b0 = W[k * 256 + tx];
        float b1 = W[k * 256 + tx + 64];
        float b2 = W[k * 256 + tx + 128];
        float b3 = W[k * 256 + tx + 192];
        #pragma unroll
        for (int i = 0; i < 8; ++i) {
            float a = Ap[(i << 7) + k];
            acc[i][0] += a * b0; acc[i][1] += a * b1;
            acc[i][2] += a * b2; acc[i][3] += a * b3;
        }
    }
    #pragma unroll
    for (int i = 0; i < 8; ++i) {
        int mm = m0 + ty * 8 + i;
        if (mm < N) {
            #pragma unroll
            for (int c = 0; c < 4; ++c) {
                float v = acc[i][c];
                hB[(size_t)mm * 256 + c * 64 + tx] = f2bf(v);
                float ps = v * atts[c * 64 + tx];
                float pd = v * attd[c * 64 + tx];
                #pragma unroll
                for (int o = 32; o; o >>= 1) { ps += __shfl_xor(ps, o); pd += __shfl_xor(pd, o); }
                if (tx == 0) { a_s4[(size_t)mm * 4 + c] = ps; a_d4[(size_t)mm * 4 + c] = pd; }
            }
        }
    }
}

// ---------------- GEMM layers 2/3 -> hB bf16 [N][RS] (zero-padded) + a_s/a_d ----------------
template <int K, int NC, int RS>
__launch_bounds__(256)
__global__ void gemm_attn_kernel(const float* __restrict__ A, const float* __restrict__ W,
                                 const float* __restrict__ atts, const float* __restrict__ attd,
                                 ushortt* __restrict__ hB, float* __restrict__ a_s,
                                 float* __restrict__ a_d, int N) {
    __shared__ float As[32 * K];
    int m0 = blockIdx.x * 32;
    int t = threadIdx.x;
    for (int idx = t; idx < 32 * K; idx += 256) {
        int r = idx / K, c = idx % K;
        int mm = m0 + r;
        As[idx] = (mm < N) ? A[(size_t)mm * K + c] : 0.f;
    }
    __syncthreads();
    int tx = t & 63, ty = t >> 6;
    float acc[8] = {};
    const float* Ap = &As[(ty * 8) * K];
    #pragma unroll 2
    for (int k = 0; k < K; ++k) {
        float bv = (tx < NC) ? W[k * NC + tx] : 0.f;
        #pragma unroll
        for (int i = 0; i < 8; ++i) acc[i] += Ap[i * K + k] * bv;
    }
    #pragma unroll
    for (int i = 0; i < 8; ++i) {
        int mm = m0 + ty * 8 + i;
        if (mm < N) {
            if (tx < RS) hB[(size_t)mm * RS + tx] = (tx < NC) ? f2bf(acc[i]) : (ushortt)0;
            float ps = (tx < NC) ? acc[i] * atts[tx] : 0.f;
            float pd = (tx < NC) ? acc[i] * attd[tx] : 0.f;
            #pragma unroll
            for (int o = 32; o; o >>= 1) { ps += __shfl_xor(ps, o); pd += __shfl_xor(pd, o); }
            if (tx == 0) { a_s[mm] = ps; a_d[mm] = pd; }
        }
    }
}

// ---------------- alpha, layer 1 (4 heads): block=node, wave=head, layout al4[edge][4] ----------------
__launch_bounds__(256)
__global__ void alpha4_kernel(const int* __restrict__ off, const int* __restrict__ csr,
                              const float* __restrict__ a_s4, const float* __restrict__ a_d4,
                              __half* __restrict__ al4, int N) {
    int node = blockIdx.x;
    if (node >= N) return;
    int head = threadIdx.x >> 6, lane = threadIdx.x & 63;
    int beg = off[node], end = off[node + 1];
    float ad = a_d4[(size_t)node * 4 + head];
    float m = -INFINITY;
    for (int j = beg + lane; j < end; j += 64) {
        float v = a_s4[(size_t)csr[j] * 4 + head] + ad;
        v = v > 0.f ? v : NEG_SLOPE * v;
        m = fmaxf(m, v);
    }
    #pragma unroll
    for (int o = 32; o; o >>= 1) m = fmaxf(m, __shfl_xor(m, o));
    float ss = 0.f;
    for (int j = beg + lane; j < end; j += 64) {
        float v = a_s4[(size_t)csr[j] * 4 + head] + ad;
        v = v > 0.f ? v : NEG_SLOPE * v;
        ss += __expf(v - m);
    }
    #pragma unroll
    for (int o = 32; o; o >>= 1) ss += __shfl_xor(ss, o);
    float inv = 1.f / (ss + 1e-16f);
    for (int j = beg + lane; j < end; j += 64) {
        float v = a_s4[(size_t)csr[j] * 4 + head] + ad;
        v = v > 0.f ? v : NEG_SLOPE * v;
        al4[(size_t)j * 4 + head] = __float2half(__expf(v - m) * inv);
    }
}

// ---------------- alpha, single head: wave=node ----------------
__launch_bounds__(256)
__global__ void alpha1w_kernel(const int* __restrict__ off, const int* __restrict__ csr,
                               const float* __restrict__ a_s, const float* __restrict__ a_d,
                               __half* __restrict__ al, int N) {
    int node = blockIdx.x * 4 + (threadIdx.x >> 6);
    int lane = threadIdx.x & 63;
    if (node >= N) return;
    int beg = off[node], end = off[node + 1];
    float ad = a_d[node];
    float m = -INFINITY;
    for (int j = beg + lane; j < end; j += 64) {
        float v = a_s[csr[j]] + ad;
        v = v > 0.f ? v : NEG_SLOPE * v;
        m = fmaxf(m, v);
    }
    #pragma unroll
    for (int o = 32; o; o >>= 1) m = fmaxf(m, __shfl_xor(m, o));
    float ss = 0.f;
    for (int j = beg + lane; j < end; j += 64) {
        float v = a_s[csr[j]] + ad;
        v = v > 0.f ? v : NEG_SLOPE * v;
        ss += __expf(v - m);
    }
    #pragma unroll
    for (int o = 32; o; o >>= 1) ss += __shfl_xor(ss, o);
    float inv = 1.f / (ss + 1e-16f);
    for (int j = beg + lane; j < end; j += 64) {
        float v = a_s[csr[j]] + ad;
        v = v > 0.f ? v : NEG_SLOPE * v;
        al[j] = __float2half(__expf(v - m) * inv);
    }
}

// ---------------- PV layer 1: wave=node, 2 edges/step, lane loads 16B (8 ch) ----------------
__launch_bounds__(256)
__global__ void pv1_kernel(const int* __restrict__ off, const int* __restrict__ csr,
                           const __half* __restrict__ al4, const ushortt* __restrict__ hB,
                           const float* __restrict__ bnsc, const float* __restrict__ bnsh,
                           float* __restrict__ act, int N) {
    int node = blockIdx.x * 4 + (threadIdx.x >> 6);
    int lane = threadIdx.x & 63;
    if (node >= N) return;
    int half = lane >> 5, sub = lane & 31, head = sub >> 3;
    int beg = off[node], end = off[node + 1], deg = end - beg;
    float acc[8] = {};
    int nt = (deg + 1) >> 1;
    int j = beg + half;
    int t = 0;
    for (; t + 2 <= nt; t += 2, j += 4) {
        int jA = j, jB = j + 2;
        bool vA = jA < end, vB = jB < end;
        int sA = csr[vA ? jA : beg];
        int sB = csr[vB ? jB : beg];
        float aA = vA ? __half2float(al4[(size_t)jA * 4 + head]) : 0.f;
        float aB = vB ? __half2float(al4[(size_t)jB * 4 + head]) : 0.f;
        uint4 hA = *(const uint4*)(hB + (size_t)sA * 256 + sub * 8);
        uint4 hBv = *(const uint4*)(hB + (size_t)sB * 256 + sub * 8);
        acc8(acc, aA, hA);
        acc8(acc, aB, hBv);
    }
    for (; t < nt; ++t, j += 2) {
        bool v = j < end;
        int s = csr[v ? j : beg];
        float a = v ? __half2float(al4[(size_t)j * 4 + head]) : 0.f;
        uint4 h = *(const uint4*)(hB + (size_t)s * 256 + sub * 8);
        acc8(acc, a, h);
    }
    #pragma unroll
    for (int i = 0; i < 8; ++i) acc[i] += __shfl_xor(acc[i], 32);
    if (half == 0) {
        int g = sub * 8;
        float o[8];
        #pragma unroll
        for (int i = 0; i < 8; ++i) {
            float v = acc[i] * bnsc[g + i] + bnsh[g + i];
            o[i] = v > 0.f ? v : expm1f(v);
        }
        float4* dst = (float4*)&act[(size_t)node * 256 + g];
        dst[0] = make_float4(o[0], o[1], o[2], o[3]);
        dst[1] = make_float4(o[4], o[5], o[6], o[7]);
    }
}

// ---------------- PV layers 2/3: wave=node, 8 edges/step, 8 lanes/edge, rows 64 ch ----------------
// EPI==0: BN(+256 offset)+ELU -> out[node][64]; EPI==2: raw -> out[node][64]
template <int EPI>
__launch_bounds__(256)
__global__ void pv64_kernel(const int* __restrict__ off, const int* __restrict__ csr,
                            const __half* __restrict__ al, const ushortt* __restrict__ hB,
                            const float* __restrict__ bnsc, const float* __restrict__ bnsh,
                            float* __restrict__ out, int N) {
    int node = blockIdx.x * 4 + (threadIdx.x >> 6);
    int lane = threadIdx.x & 63;
    if (node >= N) return;
    int grp = lane >> 3, sub = lane & 7;
    int beg = off[node], end = off[node + 1], deg = end - beg;
    float acc[8] = {};
    int nt = (deg + 7) >> 3;
    int j = beg + grp;
    int t = 0;
    for (; t + 2 <= nt; t += 2, j += 16) {
        int jA = j, jB = j + 8;
        bool vA = jA < end, vB = jB < end;
        int sA = csr[vA ? jA : beg];
        int sB = csr[vB ? jB : beg];
        float aA = vA ? __half2float(al[jA < end ? jA : beg]) : 0.f;
        float aB = vB ? __half2float(al[jB < end ? jB : beg]) : 0.f;
        uint4 hA = *(const uint4*)(hB + (size_t)sA * 64 + sub * 8);
        uint4 hBv = *(const uint4*)(hB + (size_t)sB * 64 + sub * 8);
        acc8(acc, aA, hA);
        acc8(acc, aB, hBv);
    }
    for (; t < nt; ++t, j += 8) {
        bool v = j < end;
        int s = csr[v ? j : beg];
        float a = v ? __half2float(al[v ? j : beg]) : 0.f;
        uint4 h = *(const uint4*)(hB + (size_t)s * 64 + sub * 8);
        acc8(acc, a, h);
    }
    #pragma unroll
    for (int i = 0; i < 8; ++i) {
        acc[i] += __shfl_xor(acc[i], 8);
        acc[i] += __shfl_xor(acc[i], 16);
        acc[i] += __shfl_xor(acc[i], 32);
    }
    if (lane < 8) {
        int g = lane * 8;
        float o[8];
        #pragma unroll
        for (int i = 0; i < 8; ++i) {
            if (EPI == 0) {
                float v = acc[i] * bnsc[256 + g + i] + bnsh[256 + g + i];
                o[i] = v > 0.f ? v : expm1f(v);
            } else {
                o[i] = acc[i];
            }
        }
        float4* dst = (float4*)&out[(size_t)node * 64 + g];
        dst[0] = make_float4(o[0], o[1], o[2], o[3]);
        dst[1] = make_float4(o[4], o[5], o[6], o[7]);
    }
}

// ---------------- final: bias + log_softmax over 40 (rows stride 64) ----------------
__launch_bounds__(256)
__global__ void final3_kernel(const float* __restrict__ tmp3, const float* __restrict__ b3,
                              float* __restrict__ out, int N) {
    int node = blockIdx.x * 4 + (threadIdx.x >> 6);
    int lane = threadIdx.x & 63;
    if (node >= N) return;
    bool active = lane < OUT_DIM;
    float v = active ? tmp3[(size_t)node * 64 + lane] + b3[lane] : -INFINITY;
    float mx = v;
    #pragma unroll
    for (int o = 32; o; o >>= 1) mx = fmaxf(mx, __shfl_xor(mx, o));
    float ex = active ? __expf(v - mx) : 0.f;
    float s2 = ex;
    #pragma unroll
    for (int o = 32; o; o >>= 1) s2 += __shfl_xor(s2, o);
    if (active) out[(size_t)node * 40 + lane] = v - mx - logf(s2);
}

// ---------------- host ----------------
extern "C" void kernel_launch(void* const* d_in, const int* in_sizes, int n_in,
                              void* d_out, int out_size, void* d_ws, size_t ws_size,
                              hipStream_t stream) {
    const float* x      = (const float*)d_in[0];
    const int*   ei     = (const int*)d_in[1];
    const float* W1     = (const float*)d_in[2];
    const float* att_s1 = (const float*)d_in[3];
    const float* att_d1 = (const float*)d_in[4];
    const float* b1     = (const float*)d_in[5];
    const float* bn1g   = (const float*)d_in[6];
    const float* bn1b   = (const float*)d_in[7];
    const float* bn1m   = (const float*)d_in[8];
    const float* bn1v   = (const float*)d_in[9];
    const float* W2     = (const float*)d_in[10];
    const float* att_s2 = (const float*)d_in[11];
    const float* att_d2 = (const float*)d_in[12];
    const float* b2     = (const float*)d_in[13];
    const float* bn2g   = (const float*)d_in[14];
    const float* bn2b   = (const float*)d_in[15];
    const float* bn2m   = (const float*)d_in[16];
    const float* bn2v   = (const float*)d_in[17];
    const float* W3     = (const float*)d_in[18];
    const float* att_s3 = (const float*)d_in[19];
    const float* att_d3 = (const float*)d_in[20];
    const float* b3     = (const float*)d_in[21];

    const int N    = in_sizes[0] / IN_DIM;
    const int E    = in_sizes[1] / 2;
    const int Etot = E + N;

    int*   wsi = (int*)d_ws;
    float* wsf = (float*)d_ws;
    size_t p = 0;
    int*   off    = wsi + p; p += (size_t)N + 16;
    int*   cursor = wsi + p; p += (size_t)N;
    int*   flag   = wsi + p; p += 16;
    int*   csr    = wsi + p; p += (size_t)Etot;
    float* a_s    = wsf + p; p += (size_t)N * 4;
    float* a_d    = wsf + p; p += (size_t)N * 4;
    float* bnsc   = wsf + p; p += 384;
    float* bnsh   = wsf + p; p += 384;
    size_t H = p;            p += (size_t)N * 128;   // hB1; later hB23 + tmp3
    float* act    = wsf + p; p += (size_t)N * 256;
    size_t ALR = p;          p += (size_t)Etot * 2;  // al4; later al23
    if (ws_size < p * 4) return;

    ushortt* hB1  = (ushortt*)(wsf + H);
    ushortt* hB23 = (ushortt*)(wsf + H);
    float*   tmp3 = wsf + H + (size_t)N * 32;
    __half*  al4  = (__half*)(wsf + ALR);
    __half*  al23 = (__half*)(wsf + ALR);

    float* outp = (float*)d_out;

    // ---- CSR build ----
    hipMemsetAsync(off, 0, ((size_t)N + 1) * sizeof(int), stream);
    detect_kernel<<<1, 256, 0, stream>>>((const unsigned int*)ei, flag);
    {
        int blocks = (Etot + 255) / 256;
        hist_kernel<<<blocks, 256, 0, stream>>>(ei, flag, off, E, Etot);
        scan_kernel<<<1, 1024, 0, stream>>>(off, N + 1);
        hipMemcpyAsync(cursor, off, (size_t)N * sizeof(int), hipMemcpyDeviceToDevice, stream);
        scatter_kernel<<<blocks, 256, 0, stream>>>(ei, flag, cursor, csr, E, Etot);
    }
    prep_bn_kernel<<<1, 384, 0, stream>>>(b1, bn1g, bn1b, bn1m, bn1v,
                                          b2, bn2g, bn2b, bn2m, bn2v, bnsc, bnsh);

    const int gemm_blocks = (N + 31) / 32;
    const int nb4 = (N + 3) / 4;

    // ---- layer 1 ----
    gemm1_kernel<<<gemm_blocks, 256, 0, stream>>>(x, W1, att_s1, att_d1, hB1, a_s, a_d, N);
    alpha4_kernel<<<N, 256, 0, stream>>>(off, csr, a_s, a_d, al4, N);
    pv1_kernel<<<nb4, 256, 0, stream>>>(off, csr, al4, hB1, bnsc, bnsh, act, N);

    // ---- layer 2 ----
    gemm_attn_kernel<256, 64, 64><<<gemm_blocks, 256, 0, stream>>>(act, W2, att_s2, att_d2,
                                                                   hB23, a_s, a_d, N);
    alpha1w_kernel<<<nb4, 256, 0, stream>>>(off, csr, a_s, a_d, al23, N);
    pv64_kernel<0><<<nb4, 256, 0, stream>>>(off, csr, al23, hB23, bnsc, bnsh, act, N);

    // ---- layer 3 ----
    gemm_attn_kernel<64, 40, 64><<<gemm_blocks, 256, 0, stream>>>(act, W3, att_s3, att_d3,
                                                                  hB23, a_s, a_d, N);
    alpha1w_kernel<<<nb4, 256, 0, stream>>>(off, csr, a_s, a_d, al23, N);
    pv64_kernel<2><<<nb4, 256, 0, stream>>>(off, csr, al23, hB23, bnsc, bnsh, tmp3, N);
    final3_kernel<<<nb4, 256, 0, stream>>>(tmp3, b3, outp, N);
}

// Round 5
// 988.938 us; speedup vs baseline: 1.8680x; 1.1135x over previous
//
#include <hip/hip_runtime.h>
#include <hip/hip_fp16.h>
#include <cstdint>

#define IN_DIM   128
#define HIDC     64
#define HEADS    4
#define OUT_DIM  40
#define NEG_SLOPE 0.2f
#define BN_EPS   1e-5f

typedef unsigned short ushortt;

__device__ __forceinline__ float bfval(ushortt u) {
    return __uint_as_float(((unsigned)u) << 16);
}
__device__ __forceinline__ ushortt f2bf(float f) {
    unsigned u = __float_as_uint(f);
    u += 0x7fffu + ((u >> 16) & 1u);
    return (ushortt)(u >> 16);
}
__device__ __forceinline__ unsigned pack2bf(float a, float b) {
    return (unsigned)f2bf(a) | ((unsigned)f2bf(b) << 16);
}

// acc[0..7] += a * bf16x8(h)
__device__ __forceinline__ void acc8(float* acc, float a, uint4 h) {
    unsigned u;
    u = h.x;
    acc[0] = fmaf(a, __uint_as_float(u << 16), acc[0]);
    acc[1] = fmaf(a, __uint_as_float(u & 0xffff0000u), acc[1]);
    u = h.y;
    acc[2] = fmaf(a, __uint_as_float(u << 16), acc[2]);
    acc[3] = fmaf(a, __uint_as_float(u & 0xffff0000u), acc[3]);
    u = h.z;
    acc[4] = fmaf(a, __uint_as_float(u << 16), acc[4]);
    acc[5] = fmaf(a, __uint_as_float(u & 0xffff0000u), acc[5]);
    u = h.w;
    acc[6] = fmaf(a, __uint_as_float(u << 16), acc[6]);
    acc[7] = fmaf(a, __uint_as_float(u & 0xffff0000u), acc[7]);
}

// ---------------- CSR build ----------------
__global__ void detect_kernel(const unsigned int* __restrict__ e, int* __restrict__ flag) {
    __shared__ int any;
    if (threadIdx.x == 0) any = 0;
    __syncthreads();
    for (int i = threadIdx.x; i < 1024; i += 256)
        if (e[2 * i + 1] != 0u) any = 1;
    __syncthreads();
    if (threadIdx.x == 0) flag[0] = any ? 0 : 1;   // 1 => int64
}

__device__ __forceinline__ int load_idx(const int* ei, int is64, long long pos) {
    return is64 ? ei[2 * pos] : ei[pos];
}

__global__ void hist_kernel(const int* __restrict__ ei, const int* __restrict__ flag,
                            int* __restrict__ deg, int E, int Etot) {
    int i = blockIdx.x * 256 + threadIdx.x;
    if (i >= Etot) return;
    int is64 = flag[0];
    int dst = (i < E) ? load_idx(ei, is64, (long long)E + i) : (i - E);
    atomicAdd(&deg[dst], 1);
}

__global__ void scan_kernel(int* __restrict__ data, int n) {
    __shared__ int wsum[16];
    __shared__ int chunk_total;
    int lane = threadIdx.x & 63;
    int w = threadIdx.x >> 6;
    int carry = 0;
    for (int base = 0; base < n; base += 1024) {
        int i = base + (int)threadIdx.x;
        int v = (i < n) ? data[i] : 0;
        int x = v;
        #pragma unroll
        for (int ofs = 1; ofs < 64; ofs <<= 1) {
            int y = __shfl_up(x, ofs);
            if (lane >= ofs) x += y;
        }
        if (lane == 63) wsum[w] = x;
        __syncthreads();
        if (w == 0) {
            int s = (lane < 16) ? wsum[lane] : 0;
            #pragma unroll
            for (int ofs = 1; ofs < 16; ofs <<= 1) {
                int y = __shfl_up(s, ofs);
                if (lane >= ofs) s += y;
            }
            if (lane < 16) wsum[lane] = s;
            if (lane == 15) chunk_total = s;
        }
        __syncthreads();
        int woff = (w > 0) ? wsum[w - 1] : 0;
        if (i < n) data[i] = (x + woff) - v + carry;
        int ct = chunk_total;
        __syncthreads();
        carry += ct;
    }
}

__global__ void scatter_kernel(const int* __restrict__ ei, const int* __restrict__ flag,
                               int* __restrict__ cursor, int* __restrict__ csr,
                               int E, int Etot) {
    int i = blockIdx.x * 256 + threadIdx.x;
    if (i >= Etot) return;
    int is64 = flag[0];
    int src, dst;
    if (i < E) {
        src = load_idx(ei, is64, i);
        dst = load_idx(ei, is64, (long long)E + i);
    } else {
        src = dst = i - E;
    }
    int pos = atomicAdd(&cursor[dst], 1);
    csr[pos] = src;
}

// ---------------- fold bias+BN into scale/shift ----------------
__global__ void prep_bn_kernel(const float* b1, const float* g1, const float* bb1,
                               const float* m1, const float* v1,
                               const float* b2, const float* g2, const float* bb2,
                               const float* m2, const float* v2,
                               float* __restrict__ bnsc, float* __restrict__ bnsh) {
    int t = threadIdx.x;
    if (t < 256) {
        float s = g1[t] * rsqrtf(v1[t] + BN_EPS);
        bnsc[t] = s;
        bnsh[t] = (b1[t] - m1[t]) * s + bb1[t];
    } else if (t < 320) {
        int c = t - 256;
        float s = g2[c] * rsqrtf(v2[c] + BN_EPS);
        bnsc[t] = s;
        bnsh[t] = (b2[c] - m2[c]) * s + bb2[c];
    }
}

// ---------------- register-tiled fp32 GEMM -> bf16 output ----------------
// C[M][nstride(bf16)] partial cols [n0, n0+BN) = A[M][K] @ W[K][LDW] (cols of W: n0+...).
// BM=128, BK=8, 256 threads (tm 0..15 x tn 0..15), thread tile 8 x TN.
// TN==8 (BN=128): cols split as tn*4 and 64+tn*4 for bank-conflict-free b128 reads.
// TN==4 (BN=64):  cols tn*4. W cols >= NC are zero-padded (gemm3).
template <int K, int BN, int TN, int NC, int LDW>
__launch_bounds__(256)
__global__ void gemm_tiled_kernel(const float* __restrict__ A, const float* __restrict__ W,
                                  ushortt* __restrict__ hB, int M, int nstride) {
    __shared__ float Al[8][128];
    __shared__ float Wl[8][BN];
    int m0 = blockIdx.x * 128;
    int n0 = blockIdx.y * BN;
    int t = threadIdx.x;
    int tm = t >> 4, tn = t & 15;
    float acc[8][TN] = {};
    int r = t >> 1, kq = (t & 1) * 4;

    for (int k0 = 0; k0 < K; k0 += 8) {
        // stage A tile (transposed): Al[k][m]
        float4 av = make_float4(0.f, 0.f, 0.f, 0.f);
        if (m0 + r < M) av = *(const float4*)&A[(size_t)(m0 + r) * K + k0 + kq];
        Al[kq + 0][r] = av.x; Al[kq + 1][r] = av.y;
        Al[kq + 2][r] = av.z; Al[kq + 3][r] = av.w;
        // stage W tile: Wl[k][c]
        if (BN == 128) {
            int kk = t >> 5, c4 = (t & 31) * 4;
            *(float4*)&Wl[kk][c4] = *(const float4*)&W[(size_t)(k0 + kk) * LDW + n0 + c4];
        } else {
            int kk = t >> 5, c2 = (t & 31) * 2;
            float2 wv = make_float2(0.f, 0.f);
            if (c2 + 2 <= NC) wv = *(const float2*)&W[(size_t)(k0 + kk) * LDW + n0 + c2];
            *(float2*)&Wl[kk][c2] = wv;
        }
        __syncthreads();
        #pragma unroll
        for (int k = 0; k < 8; ++k) {
            float4 a0 = *(const float4*)&Al[k][tm * 8];
            float4 a1 = *(const float4*)&Al[k][tm * 8 + 4];
            float aa[8] = {a0.x, a0.y, a0.z, a0.w, a1.x, a1.y, a1.z, a1.w};
            if (TN == 8) {
                float4 w0 = *(const float4*)&Wl[k][tn * 4];
                float4 w1 = *(const float4*)&Wl[k][64 + tn * 4];
                float ww[8] = {w0.x, w0.y, w0.z, w0.w, w1.x, w1.y, w1.z, w1.w};
                #pragma unroll
                for (int i = 0; i < 8; ++i)
                    #pragma unroll
                    for (int j = 0; j < 8; ++j)
                        acc[i][j] = fmaf(aa[i], ww[j], acc[i][j]);
            } else {
                float4 w0 = *(const float4*)&Wl[k][tn * 4];
                float ww[4] = {w0.x, w0.y, w0.z, w0.w};
                #pragma unroll
                for (int i = 0; i < 8; ++i)
                    #pragma unroll
                    for (int j = 0; j < 4; ++j)
                        acc[i][j] = fmaf(aa[i], ww[j], acc[i][j]);
            }
        }
        __syncthreads();
    }
    // epilogue: bf16 stores
    #pragma unroll
    for (int i = 0; i < 8; ++i) {
        int m = m0 + tm * 8 + i;
        if (m >= M) continue;
        ushortt* row = hB + (size_t)m * nstride + n0;
        if (TN == 8) {
            *(uint2*)(row + tn * 4) = make_uint2(pack2bf(acc[i][0], acc[i][1]),
                                                 pack2bf(acc[i][2], acc[i][3]));
            *(uint2*)(row + 64 + tn * 4) = make_uint2(pack2bf(acc[i][4], acc[i][5]),
                                                      pack2bf(acc[i][6], acc[i][7]));
        } else {
            *(uint2*)(row + tn * 4) = make_uint2(pack2bf(acc[i][0], acc[i][1]),
                                                 pack2bf(acc[i][2], acc[i][3]));
        }
    }
}

// ---------------- attention dots from bf16 h, layer1 (4 heads): wave=node ----------------
__launch_bounds__(256)
__global__ void attn_dot1_kernel(const ushortt* __restrict__ hB,
                                 const float* __restrict__ atts, const float* __restrict__ attd,
                                 float* __restrict__ a_s4, float* __restrict__ a_d4, int N) {
    int node = blockIdx.x * 4 + (threadIdx.x >> 6);
    int lane = threadIdx.x & 63;
    if (node >= N) return;
    int c0 = lane * 4;
    uint2 u = *(const uint2*)(hB + (size_t)node * 256 + c0);
    float h0 = __uint_as_float(u.x << 16);
    float h1 = __uint_as_float(u.x & 0xffff0000u);
    float h2 = __uint_as_float(u.y << 16);
    float h3 = __uint_as_float(u.y & 0xffff0000u);
    float ps = h0 * atts[c0] + h1 * atts[c0 + 1] + h2 * atts[c0 + 2] + h3 * atts[c0 + 3];
    float pd = h0 * attd[c0] + h1 * attd[c0 + 1] + h2 * attd[c0 + 2] + h3 * attd[c0 + 3];
    #pragma unroll
    for (int o = 1; o < 16; o <<= 1) {
        ps += __shfl_xor(ps, o);
        pd += __shfl_xor(pd, o);
    }
    if ((lane & 15) == 0) {
        int head = lane >> 4;
        a_s4[(size_t)node * 4 + head] = ps;
        a_d4[(size_t)node * 4 + head] = pd;
    }
}

// ---------------- attention dots, layers 2/3 (rows stride 64): wave=node ----------------
template <int NC>
__launch_bounds__(256)
__global__ void attn_dot23_kernel(const ushortt* __restrict__ hB,
                                  const float* __restrict__ atts, const float* __restrict__ attd,
                                  float* __restrict__ a_s, float* __restrict__ a_d, int N) {
    int node = blockIdx.x * 4 + (threadIdx.x >> 6);
    int lane = threadIdx.x & 63;
    if (node >= N) return;
    float h = bfval(hB[(size_t)node * 64 + lane]);
    float as = (lane < NC) ? atts[lane] : 0.f;
    float ad = (lane < NC) ? attd[lane] : 0.f;
    float ps = h * as, pd = h * ad;
    #pragma unroll
    for (int o = 32; o; o >>= 1) {
        ps += __shfl_xor(ps, o);
        pd += __shfl_xor(pd, o);
    }
    if (lane == 0) { a_s[node] = ps; a_d[node] = pd; }
}

// ---------------- alpha, layer 1 (4 heads): block=node, wave=head, layout al4[edge][4] ----------------
__launch_bounds__(256)
__global__ void alpha4_kernel(const int* __restrict__ off, const int* __restrict__ csr,
                              const float* __restrict__ a_s4, const float* __restrict__ a_d4,
                              __half* __restrict__ al4, int N) {
    int node = blockIdx.x;
    if (node >= N) return;
    int head = threadIdx.x >> 6, lane = threadIdx.x & 63;
    int beg = off[node], end = off[node + 1];
    float ad = a_d4[(size_t)node * 4 + head];
    float m = -INFINITY;
    for (int j = beg + lane; j < end; j += 64) {
        float v = a_s4[(size_t)csr[j] * 4 + head] + ad;
        v = v > 0.f ? v : NEG_SLOPE * v;
        m = fmaxf(m, v);
    }
    #pragma unroll
    for (int o = 32; o; o >>= 1) m = fmaxf(m, __shfl_xor(m, o));
    float ss = 0.f;
    for (int j = beg + lane; j < end; j += 64) {
        float v = a_s4[(size_t)csr[j] * 4 + head] + ad;
        v = v > 0.f ? v : NEG_SLOPE * v;
        ss += __expf(v - m);
    }
    #pragma unroll
    for (int o = 32; o; o >>= 1) ss += __shfl_xor(ss, o);
    float inv = 1.f / (ss + 1e-16f);
    for (int j = beg + lane; j < end; j += 64) {
        float v = a_s4[(size_t)csr[j] * 4 + head] + ad;
        v = v > 0.f ? v : NEG_SLOPE * v;
        al4[(size_t)j * 4 + head] = __float2half(__expf(v - m) * inv);
    }
}

// ---------------- alpha, single head: wave=node ----------------
__launch_bounds__(256)
__global__ void alpha1w_kernel(const int* __restrict__ off, const int* __restrict__ csr,
                               const float* __restrict__ a_s, const float* __restrict__ a_d,
                               __half* __restrict__ al, int N) {
    int node = blockIdx.x * 4 + (threadIdx.x >> 6);
    int lane = threadIdx.x & 63;
    if (node >= N) return;
    int beg = off[node], end = off[node + 1];
    float ad = a_d[node];
    float m = -INFINITY;
    for (int j = beg + lane; j < end; j += 64) {
        float v = a_s[csr[j]] + ad;
        v = v > 0.f ? v : NEG_SLOPE * v;
        m = fmaxf(m, v);
    }
    #pragma unroll
    for (int o = 32; o; o >>= 1) m = fmaxf(m, __shfl_xor(m, o));
    float ss = 0.f;
    for (int j = beg + lane; j < end; j += 64) {
        float v = a_s[csr[j]] + ad;
        v = v > 0.f ? v : NEG_SLOPE * v;
        ss += __expf(v - m);
    }
    #pragma unroll
    for (int o = 32; o; o >>= 1) ss += __shfl_xor(ss, o);
    float inv = 1.f / (ss + 1e-16f);
    for (int j = beg + lane; j < end; j += 64) {
        float v = a_s[csr[j]] + ad;
        v = v > 0.f ? v : NEG_SLOPE * v;
        al[j] = __float2half(__expf(v - m) * inv);
    }
}

// ---------------- PV layer 1: wave=node, 2 edges/step, lane loads 16B (8 ch) ----------------
__launch_bounds__(256)
__global__ void pv1_kernel(const int* __restrict__ off, const int* __restrict__ csr,
                           const __half* __restrict__ al4, const ushortt* __restrict__ hB,
                           const float* __restrict__ bnsc, const float* __restrict__ bnsh,
                           float* __restrict__ act, int N) {
    int node = blockIdx.x * 4 + (threadIdx.x >> 6);
    int lane = threadIdx.x & 63;
    if (node >= N) return;
    int half = lane >> 5, sub = lane & 31, head = sub >> 3;
    int beg = off[node], end = off[node + 1], deg = end - beg;
    float acc[8] = {};
    int nt = (deg + 1) >> 1;
    int j = beg + half;
    int t = 0;
    for (; t + 2 <= nt; t += 2, j += 4) {
        int jA = j, jB = j + 2;
        bool vA = jA < end, vB = jB < end;
        int sA = csr[vA ? jA : beg];
        int sB = csr[vB ? jB : beg];
        float aA = vA ? __half2float(al4[(size_t)jA * 4 + head]) : 0.f;
        float aB = vB ? __half2float(al4[(size_t)jB * 4 + head]) : 0.f;
        uint4 hA = *(const uint4*)(hB + (size_t)sA * 256 + sub * 8);
        uint4 hBv = *(const uint4*)(hB + (size_t)sB * 256 + sub * 8);
        acc8(acc, aA, hA);
        acc8(acc, aB, hBv);
    }
    for (; t < nt; ++t, j += 2) {
        bool v = j < end;
        int s = csr[v ? j : beg];
        float a = v ? __half2float(al4[(size_t)j * 4 + head]) : 0.f;
        uint4 h = *(const uint4*)(hB + (size_t)s * 256 + sub * 8);
        acc8(acc, a, h);
    }
    #pragma unroll
    for (int i = 0; i < 8; ++i) acc[i] += __shfl_xor(acc[i], 32);
    if (half == 0) {
        int g = sub * 8;
        float o[8];
        #pragma unroll
        for (int i = 0; i < 8; ++i) {
            float v = acc[i] * bnsc[g + i] + bnsh[g + i];
            o[i] = v > 0.f ? v : expm1f(v);
        }
        float4* dst = (float4*)&act[(size_t)node * 256 + g];
        dst[0] = make_float4(o[0], o[1], o[2], o[3]);
        dst[1] = make_float4(o[4], o[5], o[6], o[7]);
    }
}

// ---------------- PV layers 2/3: wave=node, 8 edges/step, 8 lanes/edge, rows 64 ch ----------------
// EPI==0: BN(+256 offset)+ELU -> out[node][64]; EPI==2: raw -> out[node][64]
template <int EPI>
__launch_bounds__(256)
__global__ void pv64_kernel(const int* __restrict__ off, const int* __restrict__ csr,
                            const __half* __restrict__ al, const ushortt* __restrict__ hB,
                            const float* __restrict__ bnsc, const float* __restrict__ bnsh,
                            float* __restrict__ out, int N) {
    int node = blockIdx.x * 4 + (threadIdx.x >> 6);
    int lane = threadIdx.x & 63;
    if (node >= N) return;
    int grp = lane >> 3, sub = lane & 7;
    int beg = off[node], end = off[node + 1], deg = end - beg;
    float acc[8] = {};
    int nt = (deg + 7) >> 3;
    int j = beg + grp;
    int t = 0;
    for (; t + 2 <= nt; t += 2, j += 16) {
        int jA = j, jB = j + 8;
        bool vA = jA < end, vB = jB < end;
        int sA = csr[vA ? jA : beg];
        int sB = csr[vB ? jB : beg];
        float aA = vA ? __half2float(al[vA ? jA : beg]) : 0.f;
        float aB = vB ? __half2float(al[vB ? jB : beg]) : 0.f;
        uint4 hA = *(const uint4*)(hB + (size_t)sA * 64 + sub * 8);
        uint4 hBv = *(const uint4*)(hB + (size_t)sB * 64 + sub * 8);
        acc8(acc, aA, hA);
        acc8(acc, aB, hBv);
    }
    for (; t < nt; ++t, j += 8) {
        bool v = j < end;
        int s = csr[v ? j : beg];
        float a = v ? __half2float(al[v ? j : beg]) : 0.f;
        uint4 h = *(const uint4*)(hB + (size_t)s * 64 + sub * 8);
        acc8(acc, a, h);
    }
    #pragma unroll
    for (int i = 0; i < 8; ++i) {
        acc[i] += __shfl_xor(acc[i], 8);
        acc[i] += __shfl_xor(acc[i], 16);
        acc[i] += __shfl_xor(acc[i], 32);
    }
    if (lane < 8) {
        int g = lane * 8;
        float o[8];
        #pragma unroll
        for (int i = 0; i < 8; ++i) {
            if (EPI == 0) {
                float v = acc[i] * bnsc[256 + g + i] + bnsh[256 + g + i];
                o[i] = v > 0.f ? v : expm1f(v);
            } else {
                o[i] = acc[i];
            }
        }
        float4* dst = (float4*)&out[(size_t)node * 64 + g];
        dst[0] = make_float4(o[0], o[1], o[2], o[3]);
        dst[1] = make_float4(o[4], o[5], o[6], o[7]);
    }
}

// ---------------- final: bias + log_softmax over 40 (rows stride 64) ----------------
__launch_bounds__(256)
__global__ void final3_kernel(const float* __restrict__ tmp3, const float* __restrict__ b3,
                              float* __restrict__ out, int N) {
    int node = blockIdx.x * 4 + (threadIdx.x >> 6);
    int lane = threadIdx.x & 63;
    if (node >= N) return;
    bool active = lane < OUT_DIM;
    float v = active ? tmp3[(size_t)node * 64 + lane] + b3[lane] : -INFINITY;
    float mx = v;
    #pragma unroll
    for (int o = 32; o; o >>= 1) mx = fmaxf(mx, __shfl_xor(mx, o));
    float ex = active ? __expf(v - mx) : 0.f;
    float s2 = ex;
    #pragma unroll
    for (int o = 32; o; o >>= 1) s2 += __shfl_xor(s2, o);
    if (active) out[(size_t)node * 40 + lane] = v - mx - logf(s2);
}

// ---------------- host ----------------
extern "C" void kernel_launch(void* const* d_in, const int* in_sizes, int n_in,
                              void* d_out, int out_size, void* d_ws, size_t ws_size,
                              hipStream_t stream) {
    const float* x      = (const float*)d_in[0];
    const int*   ei     = (const int*)d_in[1];
    const float* W1     = (const float*)d_in[2];
    const float* att_s1 = (const float*)d_in[3];
    const float* att_d1 = (const float*)d_in[4];
    const float* b1     = (const float*)d_in[5];
    const float* bn1g   = (const float*)d_in[6];
    const float* bn1b   = (const float*)d_in[7];
    const float* bn1m   = (const float*)d_in[8];
    const float* bn1v   = (const float*)d_in[9];
    const float* W2     = (const float*)d_in[10];
    const float* att_s2 = (const float*)d_in[11];
    const float* att_d2 = (const float*)d_in[12];
    const float* b2     = (const float*)d_in[13];
    const float* bn2g   = (const float*)d_in[14];
    const float* bn2b   = (const float*)d_in[15];
    const float* bn2m   = (const float*)d_in[16];
    const float* bn2v   = (const float*)d_in[17];
    const float* W3     = (const float*)d_in[18];
    const float* att_s3 = (const float*)d_in[19];
    const float* att_d3 = (const float*)d_in[20];
    const float* b3     = (const float*)d_in[21];

    const int N    = in_sizes[0] / IN_DIM;
    const int E    = in_sizes[1] / 2;
    const int Etot = E + N;

    int*   wsi = (int*)d_ws;
    float* wsf = (float*)d_ws;
    size_t p = 0;
    int*   off    = wsi + p; p += (size_t)N + 16;
    int*   cursor = wsi + p; p += (size_t)N;
    int*   flag   = wsi + p; p += 16;
    int*   csr    = wsi + p; p += (size_t)Etot;
    float* a_s    = wsf + p; p += (size_t)N * 4;
    float* a_d    = wsf + p; p += (size_t)N * 4;
    float* bnsc   = wsf + p; p += 384;
    float* bnsh   = wsf + p; p += 384;
    size_t H = p;            p += (size_t)N * 128;   // hB1; later hB23 + tmp3
    float* act    = wsf + p; p += (size_t)N * 256;
    size_t ALR = p;          p += (size_t)Etot * 2;  // al4; later al23
    if (ws_size < p * 4) return;

    ushortt* hB1  = (ushortt*)(wsf + H);
    ushortt* hB23 = (ushortt*)(wsf + H);
    float*   tmp3 = wsf + H + (size_t)N * 32;
    __half*  al4  = (__half*)(wsf + ALR);
    __half*  al23 = (__half*)(wsf + ALR);

    float* outp = (float*)d_out;

    // ---- CSR build ----
    hipMemsetAsync(off, 0, ((size_t)N + 1) * sizeof(int), stream);
    detect_kernel<<<1, 256, 0, stream>>>((const unsigned int*)ei, flag);
    {
        int blocks = (Etot + 255) / 256;
        hist_kernel<<<blocks, 256, 0, stream>>>(ei, flag, off, E, Etot);
        scan_kernel<<<1, 1024, 0, stream>>>(off, N + 1);
        hipMemcpyAsync(cursor, off, (size_t)N * sizeof(int), hipMemcpyDeviceToDevice, stream);
        scatter_kernel<<<blocks, 256, 0, stream>>>(ei, flag, cursor, csr, E, Etot);
    }
    prep_bn_kernel<<<1, 384, 0, stream>>>(b1, bn1g, bn1b, bn1m, bn1v,
                                          b2, bn2g, bn2b, bn2m, bn2v, bnsc, bnsh);

    const int gm = (N + 127) / 128;
    const int nb4 = (N + 3) / 4;

    // ---- layer 1 ----
    gemm_tiled_kernel<128, 128, 8, 256, 256><<<dim3(gm, 2), 256, 0, stream>>>(x, W1, hB1, N, 256);
    attn_dot1_kernel<<<nb4, 256, 0, stream>>>(hB1, att_s1, att_d1, a_s, a_d, N);
    alpha4_kernel<<<N, 256, 0, stream>>>(off, csr, a_s, a_d, al4, N);
    pv1_kernel<<<nb4, 256, 0, stream>>>(off, csr, al4, hB1, bnsc, bnsh, act, N);

    // ---- layer 2 ----
    gemm_tiled_kernel<256, 64, 4, 64, 64><<<dim3(gm, 1), 256, 0, stream>>>(act, W2, hB23, N, 64);
    attn_dot23_kernel<64><<<nb4, 256, 0, stream>>>(hB23, att_s2, att_d2, a_s, a_d, N);
    alpha1w_kernel<<<nb4, 256, 0, stream>>>(off, csr, a_s, a_d, al23, N);
    pv64_kernel<0><<<nb4, 256, 0, stream>>>(off, csr, al23, hB23, bnsc, bnsh, act, N);

    // ---- layer 3 ----
    gemm_tiled_kernel<64, 64, 4, 40, 40><<<dim3(gm, 1), 256, 0, stream>>>(act, W3, hB23, N, 64);
    attn_dot23_kernel<40><<<nb4, 256, 0, stream>>>(hB23, att_s3, att_d3, a_s, a_d, N);
    alpha1w_kernel<<<nb4, 256, 0, stream>>>(off, csr, a_s, a_d, al23, N);
    pv64_kernel<2><<<nb4, 256, 0, stream>>>(off, csr, al23, hB23, bnsc, bnsh, tmp3, N);
    final3_kernel<<<nb4, 256, 0, stream>>>(tmp3, b3, outp, N);
}

// Round 7
// 952.761 us; speedup vs baseline: 1.9389x; 1.0380x over previous
//
#include <hip/hip_runtime.h>
#include <hip/hip_fp16.h>
#include <cstdint>

#define IN_DIM   128
#define HIDC     64
#define HEADS    4
#define OUT_DIM  40
#define NEG_SLOPE 0.2f
#define BN_EPS   1e-5f

typedef unsigned short ushortt;
typedef float fx4 __attribute__((ext_vector_type(4)));

__device__ __forceinline__ float bfval(ushortt u) {
    return __uint_as_float(((unsigned)u) << 16);
}
__device__ __forceinline__ ushortt f2bf(float f) {
    unsigned u = __float_as_uint(f);
    u += 0x7fffu + ((u >> 16) & 1u);
    return (ushortt)(u >> 16);
}
__device__ __forceinline__ unsigned pack2bf(float a, float b) {
    return (unsigned)f2bf(a) | ((unsigned)f2bf(b) << 16);
}
__device__ __forceinline__ void nt_store4(float* p, float a, float b, float c, float d) {
    fx4 v = {a, b, c, d};
    __builtin_nontemporal_store(v, (fx4*)p);
}

// acc[0..7] += a * bf16x8(h)
__device__ __forceinline__ void acc8(float* acc, float a, uint4 h) {
    unsigned u;
    u = h.x;
    acc[0] = fmaf(a, __uint_as_float(u << 16), acc[0]);
    acc[1] = fmaf(a, __uint_as_float(u & 0xffff0000u), acc[1]);
    u = h.y;
    acc[2] = fmaf(a, __uint_as_float(u << 16), acc[2]);
    acc[3] = fmaf(a, __uint_as_float(u & 0xffff0000u), acc[3]);
    u = h.z;
    acc[4] = fmaf(a, __uint_as_float(u << 16), acc[4]);
    acc[5] = fmaf(a, __uint_as_float(u & 0xffff0000u), acc[5]);
    u = h.w;
    acc[6] = fmaf(a, __uint_as_float(u << 16), acc[6]);
    acc[7] = fmaf(a, __uint_as_float(u & 0xffff0000u), acc[7]);
}

// ---------------- CSR build ----------------
__global__ void detect_kernel(const unsigned int* __restrict__ e, int* __restrict__ flag) {
    __shared__ int any;
    if (threadIdx.x == 0) any = 0;
    __syncthreads();
    for (int i = threadIdx.x; i < 1024; i += 256)
        if (e[2 * i + 1] != 0u) any = 1;
    __syncthreads();
    if (threadIdx.x == 0) flag[0] = any ? 0 : 1;   // 1 => int64
}

__device__ __forceinline__ int load_idx(const int* ei, int is64, long long pos) {
    return is64 ? ei[2 * pos] : ei[pos];
}

__global__ void hist_kernel(const int* __restrict__ ei, const int* __restrict__ flag,
                            int* __restrict__ deg, int E, int Etot) {
    int i = blockIdx.x * 256 + threadIdx.x;
    if (i >= Etot) return;
    int is64 = flag[0];
    int dst = (i < E) ? load_idx(ei, is64, (long long)E + i) : (i - E);
    atomicAdd(&deg[dst], 1);
}

__global__ void scan_kernel(int* __restrict__ data, int n) {
    __shared__ int wsum[16];
    __shared__ int chunk_total;
    int lane = threadIdx.x & 63;
    int w = threadIdx.x >> 6;
    int carry = 0;
    for (int base = 0; base < n; base += 1024) {
        int i = base + (int)threadIdx.x;
        int v = (i < n) ? data[i] : 0;
        int x = v;
        #pragma unroll
        for (int ofs = 1; ofs < 64; ofs <<= 1) {
            int y = __shfl_up(x, ofs);
            if (lane >= ofs) x += y;
        }
        if (lane == 63) wsum[w] = x;
        __syncthreads();
        if (w == 0) {
            int s = (lane < 16) ? wsum[lane] : 0;
            #pragma unroll
            for (int ofs = 1; ofs < 16; ofs <<= 1) {
                int y = __shfl_up(s, ofs);
                if (lane >= ofs) s += y;
            }
            if (lane < 16) wsum[lane] = s;
            if (lane == 15) chunk_total = s;
        }
        __syncthreads();
        int woff = (w > 0) ? wsum[w - 1] : 0;
        if (i < n) data[i] = (x + woff) - v + carry;
        int ct = chunk_total;
        __syncthreads();
        carry += ct;
    }
}

__global__ void scatter_kernel(const int* __restrict__ ei, const int* __restrict__ flag,
                               int* __restrict__ cursor, int* __restrict__ csr,
                               int E, int Etot) {
    int i = blockIdx.x * 256 + threadIdx.x;
    if (i >= Etot) return;
    int is64 = flag[0];
    int src, dst;
    if (i < E) {
        src = load_idx(ei, is64, i);
        dst = load_idx(ei, is64, (long long)E + i);
    } else {
        src = dst = i - E;
    }
    int pos = atomicAdd(&cursor[dst], 1);
    csr[pos] = src;
}

// ---------------- fold bias+BN into scale/shift ----------------
__global__ void prep_bn_kernel(const float* b1, const float* g1, const float* bb1,
                               const float* m1, const float* v1,
                               const float* b2, const float* g2, const float* bb2,
                               const float* m2, const float* v2,
                               float* __restrict__ bnsc, float* __restrict__ bnsh) {
    int t = threadIdx.x;
    if (t < 256) {
        float s = g1[t] * rsqrtf(v1[t] + BN_EPS);
        bnsc[t] = s;
        bnsh[t] = (b1[t] - m1[t]) * s + bb1[t];
    } else if (t < 320) {
        int c = t - 256;
        float s = g2[c] * rsqrtf(v2[c] + BN_EPS);
        bnsc[t] = s;
        bnsh[t] = (b2[c] - m2[c]) * s + bb2[c];
    }
}

// ---------------- register-tiled fp32 GEMM -> bf16 output ----------------
template <int K, int BN, int TN, int NC, int LDW>
__launch_bounds__(256)
__global__ void gemm_tiled_kernel(const float* __restrict__ A, const float* __restrict__ W,
                                  ushortt* __restrict__ hB, int M, int nstride) {
    __shared__ float Al[8][128];
    __shared__ float Wl[8][BN];
    int m0 = blockIdx.x * 128;
    int n0 = blockIdx.y * BN;
    int t = threadIdx.x;
    int tm = t >> 4, tn = t & 15;
    float acc[8][TN] = {};
    int r = t >> 1, kq = (t & 1) * 4;

    for (int k0 = 0; k0 < K; k0 += 8) {
        float4 av = make_float4(0.f, 0.f, 0.f, 0.f);
        if (m0 + r < M) av = *(const float4*)&A[(size_t)(m0 + r) * K + k0 + kq];
        Al[kq + 0][r] = av.x; Al[kq + 1][r] = av.y;
        Al[kq + 2][r] = av.z; Al[kq + 3][r] = av.w;
        if constexpr (BN == 128) {
            int kk = t >> 5, c4 = (t & 31) * 4;
            *(float4*)&Wl[kk][c4] = *(const float4*)&W[(size_t)(k0 + kk) * LDW + n0 + c4];
        } else {
            int kk = t >> 5, c2 = (t & 31) * 2;
            float2 wv = make_float2(0.f, 0.f);
            if (c2 + 2 <= NC) wv = *(const float2*)&W[(size_t)(k0 + kk) * LDW + n0 + c2];
            *(float2*)&Wl[kk][c2] = wv;
        }
        __syncthreads();
        #pragma unroll
        for (int k = 0; k < 8; ++k) {
            float4 a0 = *(const float4*)&Al[k][tm * 8];
            float4 a1 = *(const float4*)&Al[k][tm * 8 + 4];
            float aa[8] = {a0.x, a0.y, a0.z, a0.w, a1.x, a1.y, a1.z, a1.w};
            if constexpr (TN == 8) {
                float4 w0 = *(const float4*)&Wl[k][tn * 4];
                float4 w1 = *(const float4*)&Wl[k][64 + tn * 4];
                float ww[8] = {w0.x, w0.y, w0.z, w0.w, w1.x, w1.y, w1.z, w1.w};
                #pragma unroll
                for (int i = 0; i < 8; ++i)
                    #pragma unroll
                    for (int j = 0; j < 8; ++j)
                        acc[i][j] = fmaf(aa[i], ww[j], acc[i][j]);
            } else {
                float4 w0 = *(const float4*)&Wl[k][tn * 4];
                float ww[4] = {w0.x, w0.y, w0.z, w0.w};
                #pragma unroll
                for (int i = 0; i < 8; ++i)
                    #pragma unroll
                    for (int j = 0; j < 4; ++j)
                        acc[i][j] = fmaf(aa[i], ww[j], acc[i][j]);
            }
        }
        __syncthreads();
    }
    #pragma unroll
    for (int i = 0; i < 8; ++i) {
        int m = m0 + tm * 8 + i;
        if (m >= M) continue;
        ushortt* row = hB + (size_t)m * nstride + n0;
        if constexpr (TN == 8) {
            *(uint2*)(row + tn * 4) = make_uint2(pack2bf(acc[i][0], acc[i][1]),
                                                 pack2bf(acc[i][2], acc[i][3]));
            *(uint2*)(row + 64 + tn * 4) = make_uint2(pack2bf(acc[i][4], acc[i][5]),
                                                      pack2bf(acc[i][6], acc[i][7]));
        } else {
            *(uint2*)(row + tn * 4) = make_uint2(pack2bf(acc[i][0], acc[i][1]),
                                                 pack2bf(acc[i][2], acc[i][3]));
        }
    }
}

// ---------------- attention dots from bf16 h, layer1 (4 heads): wave=node ----------------
__launch_bounds__(256)
__global__ void attn_dot1_kernel(const ushortt* __restrict__ hB,
                                 const float* __restrict__ atts, const float* __restrict__ attd,
                                 float* __restrict__ a_s4, float* __restrict__ a_d4, int N) {
    int node = blockIdx.x * 4 + (threadIdx.x >> 6);
    int lane = threadIdx.x & 63;
    if (node >= N) return;
    int c0 = lane * 4;
    uint2 u = *(const uint2*)(hB + (size_t)node * 256 + c0);
    float h0 = __uint_as_float(u.x << 16);
    float h1 = __uint_as_float(u.x & 0xffff0000u);
    float h2 = __uint_as_float(u.y << 16);
    float h3 = __uint_as_float(u.y & 0xffff0000u);
    float ps = h0 * atts[c0] + h1 * atts[c0 + 1] + h2 * atts[c0 + 2] + h3 * atts[c0 + 3];
    float pd = h0 * attd[c0] + h1 * attd[c0 + 1] + h2 * attd[c0 + 2] + h3 * attd[c0 + 3];
    #pragma unroll
    for (int o = 1; o < 16; o <<= 1) {
        ps += __shfl_xor(ps, o);
        pd += __shfl_xor(pd, o);
    }
    if ((lane & 15) == 0) {
        int head = lane >> 4;
        a_s4[(size_t)node * 4 + head] = ps;
        a_d4[(size_t)node * 4 + head] = pd;
    }
}

// ---------------- attention dots, layers 2/3 (rows stride 64): wave=node ----------------
template <int NC>
__launch_bounds__(256)
__global__ void attn_dot23_kernel(const ushortt* __restrict__ hB,
                                  const float* __restrict__ atts, const float* __restrict__ attd,
                                  float* __restrict__ a_s, float* __restrict__ a_d, int N) {
    int node = blockIdx.x * 4 + (threadIdx.x >> 6);
    int lane = threadIdx.x & 63;
    if (node >= N) return;
    float h = bfval(hB[(size_t)node * 64 + lane]);
    float as = (lane < NC) ? atts[lane] : 0.f;
    float ad = (lane < NC) ? attd[lane] : 0.f;
    float ps = h * as, pd = h * ad;
    #pragma unroll
    for (int o = 32; o; o >>= 1) {
        ps += __shfl_xor(ps, o);
        pd += __shfl_xor(pd, o);
    }
    if (lane == 0) { a_s[node] = ps; a_d[node] = pd; }
}

// ---------------- alpha layer 1 (4 heads): ONE gather walk + sequential exp walk ----------------
__launch_bounds__(256)
__global__ void alpha4_kernel(const int* __restrict__ off, const int* __restrict__ csr,
                              const float* __restrict__ a_s4, const float* __restrict__ a_d4,
                              __half* __restrict__ al4, float* __restrict__ invb, int N) {
    int node = blockIdx.x;
    if (node >= N) return;
    int head = threadIdx.x >> 6, lane = threadIdx.x & 63;
    int beg = off[node], end = off[node + 1];
    float ad = a_d4[(size_t)node * 4 + head];
    float m = -INFINITY;
    for (int j = beg + lane; j < end; j += 64) {
        float v = a_s4[(size_t)csr[j] * 4 + head] + ad;
        v = v > 0.f ? v : NEG_SLOPE * v;
        al4[(size_t)j * 4 + head] = __float2half(v);
        m = fmaxf(m, v);
    }
    #pragma unroll
    for (int o = 32; o; o >>= 1) m = fmaxf(m, __shfl_xor(m, o));
    float ss = 0.f;
    for (int j = beg + lane; j < end; j += 64) {
        float v = __half2float(al4[(size_t)j * 4 + head]);
        float e = __expf(v - m);
        al4[(size_t)j * 4 + head] = __float2half(e);
        ss += e;
    }
    #pragma unroll
    for (int o = 32; o; o >>= 1) ss += __shfl_xor(ss, o);
    if (lane == 0) invb[(size_t)node * 4 + head] = 1.f / (ss + 1e-16f);
}

// ---------------- alpha single head: same 2-walk scheme, wave=node ----------------
__launch_bounds__(256)
__global__ void alpha1w_kernel(const int* __restrict__ off, const int* __restrict__ csr,
                               const float* __restrict__ a_s, const float* __restrict__ a_d,
                               __half* __restrict__ al, float* __restrict__ invb, int N) {
    int node = blockIdx.x * 4 + (threadIdx.x >> 6);
    int lane = threadIdx.x & 63;
    if (node >= N) return;
    int beg = off[node], end = off[node + 1];
    float ad = a_d[node];
    float m = -INFINITY;
    for (int j = beg + lane; j < end; j += 64) {
        float v = a_s[csr[j]] + ad;
        v = v > 0.f ? v : NEG_SLOPE * v;
        al[j] = __float2half(v);
        m = fmaxf(m, v);
    }
    #pragma unroll
    for (int o = 32; o; o >>= 1) m = fmaxf(m, __shfl_xor(m, o));
    float ss = 0.f;
    for (int j = beg + lane; j < end; j += 64) {
        float v = __half2float(al[j]);
        float e = __expf(v - m);
        al[j] = __float2half(e);
        ss += e;
    }
    #pragma unroll
    for (int o = 32; o; o >>= 1) ss += __shfl_xor(ss, o);
    if (lane == 0) invb[node] = 1.f / (ss + 1e-16f);
}

// ---------------- PV layer 1: wave=node, unroll 4 (8 gathers in flight), 32-bit offsets ----------------
__launch_bounds__(256)
__global__ void pv1_kernel(const int* __restrict__ off, const int* __restrict__ csr,
                           const __half* __restrict__ al4, const ushortt* __restrict__ hB,
                           const float* __restrict__ invb,
                           const float* __restrict__ bnsc, const float* __restrict__ bnsh,
                           float* __restrict__ act, int N) {
    int node = blockIdx.x * 4 + (threadIdx.x >> 6);
    int lane = threadIdx.x & 63;
    if (node >= N) return;
    int half = lane >> 5, sub = lane & 31, head = sub >> 3;
    unsigned subb = (unsigned)(sub * 16);
    unsigned hoff = (unsigned)(head * 2);
    int beg = off[node], end = off[node + 1], deg = end - beg;
    const char* hBb = (const char*)hB;
    const char* alb = (const char*)al4;
    float acc[8] = {};
    int nt = (deg + 1) >> 1;
    int j = beg + half;
    int t = 0;
    for (; t + 4 <= nt; t += 4, j += 8) {
        float av[4]; unsigned ro[4];
        #pragma unroll
        for (int q = 0; q < 4; ++q) {
            int jq = j + 2 * q;
            bool v = jq < end;
            int idx = v ? jq : beg;
            int s = csr[idx];
            av[q] = v ? __half2float(*(const __half*)(alb + (unsigned)idx * 8u + hoff)) : 0.f;
            ro[q] = (unsigned)s * 512u + subb;
        }
        uint4 h0 = *(const uint4*)(hBb + ro[0]);
        uint4 h1 = *(const uint4*)(hBb + ro[1]);
        uint4 h2 = *(const uint4*)(hBb + ro[2]);
        uint4 h3 = *(const uint4*)(hBb + ro[3]);
        acc8(acc, av[0], h0);
        acc8(acc, av[1], h1);
        acc8(acc, av[2], h2);
        acc8(acc, av[3], h3);
    }
    for (; t < nt; ++t, j += 2) {
        bool v = j < end;
        int idx = v ? j : beg;
        int s = csr[idx];
        float a = v ? __half2float(*(const __half*)(alb + (unsigned)idx * 8u + hoff)) : 0.f;
        uint4 h = *(const uint4*)(hBb + (unsigned)s * 512u + subb);
        acc8(acc, a, h);
    }
    #pragma unroll
    for (int i = 0; i < 8; ++i) acc[i] += __shfl_xor(acc[i], 32);
    if (half == 0) {
        float inv = invb[(size_t)node * 4 + head];
        int g = sub * 8;
        float o[8];
        #pragma unroll
        for (int i = 0; i < 8; ++i) {
            float v = acc[i] * inv * bnsc[g + i] + bnsh[g + i];
            o[i] = v > 0.f ? v : expm1f(v);
        }
        float* dst = &act[(size_t)node * 256 + g];
        nt_store4(dst, o[0], o[1], o[2], o[3]);
        nt_store4(dst + 4, o[4], o[5], o[6], o[7]);
    }
}

// ---------------- PV layers 2/3: wave=node, 8 lanes/edge, rows 64 ch ----------------
// EPI==0: *inv, BN(+256)+ELU -> out[node][64]; EPI==2: *inv, +bias, log_softmax(40) -> out[node][40]
template <int EPI>
__launch_bounds__(256)
__global__ void pv64_kernel(const int* __restrict__ off, const int* __restrict__ csr,
                            const __half* __restrict__ al, const ushortt* __restrict__ hB,
                            const float* __restrict__ invb,
                            const float* __restrict__ bnsc, const float* __restrict__ bnsh,
                            const float* __restrict__ bias,
                            float* __restrict__ out, int N) {
    int node = blockIdx.x * 4 + (threadIdx.x >> 6);
    int lane = threadIdx.x & 63;
    if (node >= N) return;
    int grp = lane >> 3, sub = lane & 7;
    unsigned subb = (unsigned)(sub * 16);
    int beg = off[node], end = off[node + 1], deg = end - beg;
    const char* hBb = (const char*)hB;
    float acc[8] = {};
    int nt = (deg + 7) >> 3;
    int j = beg + grp;
    int t = 0;
    for (; t + 2 <= nt; t += 2, j += 16) {
        int jA = j, jB = j + 8;
        bool vA = jA < end, vB = jB < end;
        int iA = vA ? jA : beg, iB = vB ? jB : beg;
        int sA = csr[iA], sB = csr[iB];
        float aA = vA ? __half2float(al[iA]) : 0.f;
        float aB = vB ? __half2float(al[iB]) : 0.f;
        uint4 hA = *(const uint4*)(hBb + (unsigned)sA * 128u + subb);
        uint4 hBv = *(const uint4*)(hBb + (unsigned)sB * 128u + subb);
        acc8(acc, aA, hA);
        acc8(acc, aB, hBv);
    }
    for (; t < nt; ++t, j += 8) {
        bool v = j < end;
        int idx = v ? j : beg;
        int s = csr[idx];
        float a = v ? __half2float(al[idx]) : 0.f;
        uint4 h = *(const uint4*)(hBb + (unsigned)s * 128u + subb);
        acc8(acc, a, h);
    }
    #pragma unroll
    for (int i = 0; i < 8; ++i) {
        acc[i] += __shfl_xor(acc[i], 8);
        acc[i] += __shfl_xor(acc[i], 16);
        acc[i] += __shfl_xor(acc[i], 32);
    }
    float inv = invb[node];
    if constexpr (EPI == 0) {
        if (lane < 8) {
            int g = lane * 8;
            float o[8];
            #pragma unroll
            for (int i = 0; i < 8; ++i) {
                float v = acc[i] * inv * bnsc[256 + g + i] + bnsh[256 + g + i];
                o[i] = v > 0.f ? v : expm1f(v);
            }
            float* dst = &out[(size_t)node * 64 + g];
            nt_store4(dst, o[0], o[1], o[2], o[3]);
            nt_store4(dst + 4, o[4], o[5], o[6], o[7]);
        }
    } else {
        // fused bias + log_softmax over the 40 valid channels (lanes 0-4 x 8 ch)
        int g = lane * 8;
        bool act8 = lane < 5;
        float val[8];
        float mx = -INFINITY;
        #pragma unroll
        for (int i = 0; i < 8; ++i) {
            val[i] = act8 ? (acc[i] * inv + bias[act8 ? (g + i) : 0]) : -INFINITY;
            mx = fmaxf(mx, val[i]);
        }
        #pragma unroll
        for (int o = 1; o < 8; o <<= 1) mx = fmaxf(mx, __shfl_xor(mx, o));
        float se = 0.f;
        if (act8) {
            #pragma unroll
            for (int i = 0; i < 8; ++i) se += __expf(val[i] - mx);
        }
        #pragma unroll
        for (int o = 1; o < 8; o <<= 1) se += __shfl_xor(se, o);
        if (act8) {
            float lse = mx + logf(se);
            float o0[8];
            #pragma unroll
            for (int i = 0; i < 8; ++i) o0[i] = val[i] - lse;
            float* dst = &out[(size_t)node * 40 + g];
            nt_store4(dst, o0[0], o0[1], o0[2], o0[3]);
            nt_store4(dst + 4, o0[4], o0[5], o0[6], o0[7]);
        }
    }
}

// ---------------- host ----------------
extern "C" void kernel_launch(void* const* d_in, const int* in_sizes, int n_in,
                              void* d_out, int out_size, void* d_ws, size_t ws_size,
                              hipStream_t stream) {
    const float* x      = (const float*)d_in[0];
    const int*   ei     = (const int*)d_in[1];
    const float* W1     = (const float*)d_in[2];
    const float* att_s1 = (const float*)d_in[3];
    const float* att_d1 = (const float*)d_in[4];
    const float* b1     = (const float*)d_in[5];
    const float* bn1g   = (const float*)d_in[6];
    const float* bn1b   = (const float*)d_in[7];
    const float* bn1m   = (const float*)d_in[8];
    const float* bn1v   = (const float*)d_in[9];
    const float* W2     = (const float*)d_in[10];
    const float* att_s2 = (const float*)d_in[11];
    const float* att_d2 = (const float*)d_in[12];
    const float* b2     = (const float*)d_in[13];
    const float* bn2g   = (const float*)d_in[14];
    const float* bn2b   = (const float*)d_in[15];
    const float* bn2m   = (const float*)d_in[16];
    const float* bn2v   = (const float*)d_in[17];
    const float* W3     = (const float*)d_in[18];
    const float* att_s3 = (const float*)d_in[19];
    const float* att_d3 = (const float*)d_in[20];
    const float* b3     = (const float*)d_in[21];

    const int N    = in_sizes[0] / IN_DIM;
    const int E    = in_sizes[1] / 2;
    const int Etot = E + N;

    int*   wsi = (int*)d_ws;
    float* wsf = (float*)d_ws;
    size_t p = 0;
    int*   off    = wsi + p; p += (size_t)N + 16;
    int*   cursor = wsi + p; p += (size_t)N;
    int*   flag   = wsi + p; p += 16;
    int*   csr    = wsi + p; p += (size_t)Etot;
    float* a_s    = wsf + p; p += (size_t)N * 4;
    float* a_d    = wsf + p; p += (size_t)N * 4;
    float* invb   = wsf + p; p += (size_t)N * 4;
    float* bnsc   = wsf + p; p += 384;
    float* bnsh   = wsf + p; p += 384;
    size_t H = p;            p += (size_t)N * 128;   // hB1 / hB23
    float* act    = wsf + p; p += (size_t)N * 256;
    size_t ALR = p;          p += (size_t)Etot * 2;  // al4 / al23
    if (ws_size < p * 4) return;

    ushortt* hB1  = (ushortt*)(wsf + H);
    ushortt* hB23 = (ushortt*)(wsf + H);
    __half*  al4  = (__half*)(wsf + ALR);
    __half*  al23 = (__half*)(wsf + ALR);

    float* outp = (float*)d_out;

    // ---- CSR build ----
    hipMemsetAsync(off, 0, ((size_t)N + 1) * sizeof(int), stream);
    detect_kernel<<<1, 256, 0, stream>>>((const unsigned int*)ei, flag);
    {
        int blocks = (Etot + 255) / 256;
        hist_kernel<<<blocks, 256, 0, stream>>>(ei, flag, off, E, Etot);
        scan_kernel<<<1, 1024, 0, stream>>>(off, N + 1);
        hipMemcpyAsync(cursor, off, (size_t)N * sizeof(int), hipMemcpyDeviceToDevice, stream);
        scatter_kernel<<<blocks, 256, 0, stream>>>(ei, flag, cursor, csr, E, Etot);
    }
    prep_bn_kernel<<<1, 384, 0, stream>>>(b1, bn1g, bn1b, bn1m, bn1v,
                                          b2, bn2g, bn2b, bn2m, bn2v, bnsc, bnsh);

    const int gm = (N + 127) / 128;
    const int nb4 = (N + 3) / 4;

    // ---- layer 1 ----
    gemm_tiled_kernel<128, 128, 8, 256, 256><<<dim3(gm, 2), 256, 0, stream>>>(x, W1, hB1, N, 256);
    attn_dot1_kernel<<<nb4, 256, 0, stream>>>(hB1, att_s1, att_d1, a_s, a_d, N);
    alpha4_kernel<<<N, 256, 0, stream>>>(off, csr, a_s, a_d, al4, invb, N);
    pv1_kernel<<<nb4, 256, 0, stream>>>(off, csr, al4, hB1, invb, bnsc, bnsh, act, N);

    // ---- layer 2 ----
    gemm_tiled_kernel<256, 64, 4, 64, 64><<<dim3(gm, 1), 256, 0, stream>>>(act, W2, hB23, N, 64);
    attn_dot23_kernel<64><<<nb4, 256, 0, stream>>>(hB23, att_s2, att_d2, a_s, a_d, N);
    alpha1w_kernel<<<nb4, 256, 0, stream>>>(off, csr, a_s, a_d, al23, invb, N);
    pv64_kernel<0><<<nb4, 256, 0, stream>>>(off, csr, al23, hB23, invb, bnsc, bnsh, nullptr, act, N);

    // ---- layer 3 (log_softmax fused into PV epilogue) ----
    gemm_tiled_kernel<64, 64, 4, 40, 40><<<dim3(gm, 1), 256, 0, stream>>>(act, W3, hB23, N, 64);
    attn_dot23_kernel<40><<<nb4, 256, 0, stream>>>(hB23, att_s3, att_d3, a_s, a_d, N);
    alpha1w_kernel<<<nb4, 256, 0, stream>>>(off, csr, a_s, a_d, al23, invb, N);
    pv64_kernel<2><<<nb4, 256, 0, stream>>>(off, csr, al23, hB23, invb, nullptr, nullptr, b3, outp, N);
}